// Round 2
// baseline (495.150 us; speedup 1.0000x reference)
//
#include <hip/hip_runtime.h>
#include <stdint.h>

// TimeSeriesAttention: x[B,T,C] -> per-head QKV -> causal softmax(QK^T/32) V -> proj
// B=4 T=2048 C=1024 H=16 D=64.
// Device I/O dtype: float32 (reference dtype). Internal compute: bf16 MFMA.
//
// ws layout (elements of bf16):
//   [0,    8M)  x_bf  [B*T][C]          bf16 copy of x
//   [8M,  11M)  wtq   3 x [n=h*64+d][k] transposed qkv weights (bf16)
//   [11M, 12M)  wtp   [c][k]            transposed proj weight (bf16)
//   [12M, 36M)  q,k,v [B*T][H*D]        each 8M elems
//   [36M, 44M)  att   [B*T][H*D]        concat-head attention output
// total 44M bf16 elems = 88MB of d_ws.

typedef uint32_t u32;
typedef __bf16 bf16x8 __attribute__((ext_vector_type(8)));
typedef unsigned short us8 __attribute__((ext_vector_type(8)));
typedef float f32x4 __attribute__((ext_vector_type(4)));

static __device__ __forceinline__ unsigned short f2bf(float f) {
  union { float f; u32 i; } cv; cv.f = f;
  u32 x = cv.i;
  u32 r = (x + 0x7fffu + ((x >> 16) & 1u)) >> 16;  // RNE
  return (unsigned short)r;
}

// async global->LDS, 16B per lane; LDS dest is wave-uniform base + lane*16.
static __device__ __forceinline__ void gload_lds16(const unsigned short* g, unsigned short* l) {
  __builtin_amdgcn_global_load_lds(
      (__attribute__((address_space(1))) u32*)g,
      (__attribute__((address_space(3))) u32*)l, 16, 0, 0);
}

// ---------------------------------------------------------------------------
// x f32 -> bf16, 8 elems/thread
__global__ __launch_bounds__(256) void cvt_f32_bf16(
    const float* __restrict__ src, unsigned short* __restrict__ dst) {
  size_t i = (size_t)(blockIdx.x * 256 + threadIdx.x) * 8u;
  float4 a = *(const float4*)(src + i);
  float4 b = *(const float4*)(src + i + 4);
  us8 v;
  v[0] = f2bf(a.x); v[1] = f2bf(a.y); v[2] = f2bf(a.z); v[3] = f2bf(a.w);
  v[4] = f2bf(b.x); v[5] = f2bf(b.y); v[6] = f2bf(b.z); v[7] = f2bf(b.w);
  *(us8*)(dst + i) = v;
}

// ---------------------------------------------------------------------------
// wq/wk/wv [H][C][D] f32 -> wt [n=h*64+d][k=c] bf16, via 64x64 LDS tiles.
// blockIdx: x = c-tile (16), y = head (16), z = matrix (3)
__global__ __launch_bounds__(256) void transpose_qkv(
    const float* __restrict__ wq, const float* __restrict__ wk,
    const float* __restrict__ wv, unsigned short* __restrict__ dst) {
  __shared__ unsigned short lds[64][68];
  const float* src = (blockIdx.z == 0) ? wq : (blockIdx.z == 1) ? wk : wv;
  unsigned short* d = dst + ((size_t)blockIdx.z << 20);
  const int tid = threadIdx.x;
  const int h = blockIdx.y, c0 = blockIdx.x * 64;
  const float* s = src + (size_t)h * 65536u + (size_t)c0 * 64u;
#pragma unroll
  for (int it = 0; it < 16; ++it) {
    int idx = it * 256 + tid;
    int r = idx >> 6, dd = idx & 63;          // read s[r][dd], coalesced
    lds[dd][r] = f2bf(s[r * 64 + dd]);
  }
  __syncthreads();
#pragma unroll
  for (int it = 0; it < 16; ++it) {
    int idx = it * 256 + tid;
    int dd = idx >> 6, r = idx & 63;          // write row h*64+dd, coalesced
    d[(size_t)(h * 64 + dd) * 1024u + c0 + r] = lds[dd][r];
  }
}

// w_proj [HD=1024][C=1024] f32 -> wtp [c][hd] bf16
// blockIdx: x = c-tile (16), y = hd-tile (16)
__global__ __launch_bounds__(256) void transpose_proj(
    const float* __restrict__ wp, unsigned short* __restrict__ dst) {
  __shared__ unsigned short lds[64][68];
  const int tid = threadIdx.x;
  const int c0 = blockIdx.x * 64, r0 = blockIdx.y * 64;
#pragma unroll
  for (int it = 0; it < 16; ++it) {
    int idx = it * 256 + tid;
    int r = idx >> 6, cc = idx & 63;          // read wp[r0+r][c0+cc], coalesced
    lds[cc][r] = f2bf(wp[(size_t)(r0 + r) * 1024u + c0 + cc]);
  }
  __syncthreads();
#pragma unroll
  for (int it = 0; it < 16; ++it) {
    int idx = it * 256 + tid;
    int cc = idx >> 6, r = idx & 63;          // write dst[c0+cc][r0+r], coalesced
    dst[(size_t)(c0 + cc) * 1024u + r0 + r] = lds[cc][r];
  }
}

// ---------------------------------------------------------------------------
// BT-GEMM: C[m][n] = sum_k A[m][k] * Bt[n][k]  (+ bias[n])
// 128x128 tile, BK=32, 4 waves in 2x2, each wave 64x64 (4x4 frags 16x16x32).
// F32OUT=1: write float with f32 bias. F32OUT=0: write bf16, z-strided out.
#define BM 128
#define BN 128
#define BK 32

template <int F32OUT>
__global__ __launch_bounds__(256) void gemm_bt(
    const unsigned short* __restrict__ A, const unsigned short* __restrict__ Bt,
    const float* __restrict__ bias, void* __restrict__ Cv,
    int M, int N, int K) {
  __shared__ __align__(16) unsigned short Al[BM * BK];
  __shared__ __align__(16) unsigned short Bl[BN * BK];
  const int tid = threadIdx.x;
  const int wid = tid >> 6, lane = tid & 63;
  const int l15 = lane & 15, lhi = lane >> 4;
  const int m0 = blockIdx.y * BM;
  const int n0 = blockIdx.x * BN;
  const int wr = wid >> 1, wc = wid & 1;
  const unsigned short* Btz = Bt + ((size_t)blockIdx.z << 20);

  f32x4 acc[4][4] = {};

  for (int k0 = 0; k0 < K; k0 += BK) {
#pragma unroll
    for (int j = 0; j < 2; ++j) {
      int q = tid + j * 256;         // chunk id 0..511
      int row = q >> 2, c = q & 3;   // [row][c*8..c*8+7]
      gload_lds16(A + (size_t)(m0 + row) * K + (k0 + c * 8), Al + q * 8);
      gload_lds16(Btz + (size_t)(n0 + row) * K + (k0 + c * 8), Bl + q * 8);
    }
    __syncthreads();
    bf16x8 af[4], bfr[4];
#pragma unroll
    for (int mi = 0; mi < 4; ++mi)
      af[mi] = *(const bf16x8*)(Al + (wr * 64 + mi * 16 + l15) * BK + lhi * 8);
#pragma unroll
    for (int ni = 0; ni < 4; ++ni)
      bfr[ni] = *(const bf16x8*)(Bl + (wc * 64 + ni * 16 + l15) * BK + lhi * 8);
#pragma unroll
    for (int mi = 0; mi < 4; ++mi)
#pragma unroll
      for (int ni = 0; ni < 4; ++ni)
        acc[mi][ni] = __builtin_amdgcn_mfma_f32_16x16x32_bf16(
            af[mi], bfr[ni], acc[mi][ni], 0, 0, 0);
    __syncthreads();
  }
#pragma unroll
  for (int mi = 0; mi < 4; ++mi) {
#pragma unroll
    for (int ni = 0; ni < 4; ++ni) {
      int n = n0 + wc * 64 + ni * 16 + l15;
      if constexpr (F32OUT) {
        float* Cz = (float*)Cv;
        float badd = bias[n];
#pragma unroll
        for (int r = 0; r < 4; ++r) {
          int m = m0 + wr * 64 + mi * 16 + lhi * 4 + r;
          Cz[(size_t)m * N + n] = acc[mi][ni][r] + badd;
        }
      } else {
        unsigned short* Cz = (unsigned short*)Cv + ((size_t)blockIdx.z << 23);
#pragma unroll
        for (int r = 0; r < 4; ++r) {
          int m = m0 + wr * 64 + mi * 16 + lhi * 4 + r;
          Cz[(size_t)m * N + n] = f2bf(acc[mi][ni][r]);
        }
      }
    }
  }
}

// ---------------------------------------------------------------------------
// Flash causal attention. One block = (b,h,q-tile of 128). 4 waves x 32 rows.
// KV tile 64. K_lds [s][d] stride 72 (pad kills row-aligned bank conflict);
// Vt_lds [d][s] stride 72; P through per-wave LDS [32][72].
#define QT 128
#define KVT 64
#define PSTR 72

__global__ __launch_bounds__(256) void attn_fwd(
    const unsigned short* __restrict__ Qg, const unsigned short* __restrict__ Kg,
    const unsigned short* __restrict__ Vg, unsigned short* __restrict__ Og) {
  __shared__ __align__(16) unsigned short Kl[KVT * PSTR];
  __shared__ __align__(16) unsigned short Vt[64 * PSTR];
  __shared__ __align__(16) unsigned short Pl[4][32 * PSTR];
  const int tid = threadIdx.x, wid = tid >> 6, lane = tid & 63;
  const int l15 = lane & 15, lhi = lane >> 4;
  const int qt = blockIdx.x;
  const int b = blockIdx.y >> 4, h = blockIdx.y & 15;
  const size_t base = ((size_t)b * 2048u) * 1024u + (size_t)h * 64u;
  const int qrow0 = qt * QT + wid * 32;

  // Q fragments in registers: rows qrow0..+31, k = d (64) in 2 chunks
  bf16x8 qf[2][2];
#pragma unroll
  for (int fi = 0; fi < 2; ++fi)
#pragma unroll
    for (int kj = 0; kj < 2; ++kj)
      qf[fi][kj] = *(const bf16x8*)(Qg + base +
          (size_t)(qrow0 + fi * 16 + l15) * 1024u + kj * 32 + lhi * 8);

  float mrun[2][4], lrun[2][4];
  f32x4 oacc[2][4] = {};
#pragma unroll
  for (int fi = 0; fi < 2; ++fi)
#pragma unroll
    for (int r = 0; r < 4; ++r) { mrun[fi][r] = -1e30f; lrun[fi][r] = 0.0f; }

  const int ntiles = (qt * QT + QT) / KVT;  // causal: tiles 0..2qt+1
  for (int kt = 0; kt < ntiles; ++kt) {
    const int s0 = kt * KVT;
    __syncthreads();  // prev iter's LDS reads done before restaging
#pragma unroll
    for (int j = 0; j < 2; ++j) {
      int q = tid + j * 256;        // 512 chunks of 8 elems
      int s = q >> 3, c = q & 7;
      us8 kv = *(const us8*)(Kg + base + (size_t)(s0 + s) * 1024u + c * 8);
      *(us8*)(Kl + s * PSTR + c * 8) = kv;
      us8 vv = *(const us8*)(Vg + base + (size_t)(s0 + s) * 1024u + c * 8);
#pragma unroll
      for (int jj = 0; jj < 8; ++jj)
        Vt[(c * 8 + jj) * PSTR + s] = vv[jj];
    }
    __syncthreads();

    // S = Q K^T
    f32x4 sacc[2][4] = {};
#pragma unroll
    for (int kj = 0; kj < 2; ++kj) {
      bf16x8 kf[4];
#pragma unroll
      for (int sj = 0; sj < 4; ++sj)
        kf[sj] = *(const bf16x8*)(Kl + (sj * 16 + l15) * PSTR + kj * 32 + lhi * 8);
#pragma unroll
      for (int fi = 0; fi < 2; ++fi)
#pragma unroll
        for (int sj = 0; sj < 4; ++sj)
          sacc[fi][sj] = __builtin_amdgcn_mfma_f32_16x16x32_bf16(
              qf[fi][kj], kf[sj], sacc[fi][sj], 0, 0, 0);
    }

    // scale 1/32, causal mask, per-row tile max
    float tmax[2][4];
#pragma unroll
    for (int fi = 0; fi < 2; ++fi)
#pragma unroll
      for (int r = 0; r < 4; ++r) {
        int row = qt * QT + wid * 32 + fi * 16 + lhi * 4 + r;
        float mx = -1e30f;
#pragma unroll
        for (int sj = 0; sj < 4; ++sj) {
          int col = s0 + sj * 16 + l15;
          float v = sacc[fi][sj][r] * 0.03125f;
          v = (col <= row) ? v : -1e30f;
          sacc[fi][sj][r] = v;
          mx = fmaxf(mx, v);
        }
        tmax[fi][r] = mx;
      }
#pragma unroll
    for (int d = 1; d < 16; d <<= 1)
#pragma unroll
      for (int fi = 0; fi < 2; ++fi)
#pragma unroll
        for (int r = 0; r < 4; ++r)
          tmax[fi][r] = fmaxf(tmax[fi][r], __shfl_xor(tmax[fi][r], d, 64));

    // online-softmax rescale
    float sc[2][4];
#pragma unroll
    for (int fi = 0; fi < 2; ++fi)
#pragma unroll
      for (int r = 0; r < 4; ++r) {
        float mnew = fmaxf(mrun[fi][r], tmax[fi][r]);
        sc[fi][r] = __expf(mrun[fi][r] - mnew);
        mrun[fi][r] = mnew;
        lrun[fi][r] *= sc[fi][r];
      }
#pragma unroll
    for (int fi = 0; fi < 2; ++fi)
#pragma unroll
      for (int dj = 0; dj < 4; ++dj)
#pragma unroll
        for (int r = 0; r < 4; ++r)
          oacc[fi][dj][r] *= sc[fi][r];

    // P = exp(S - m), row-sum, stash P (bf16) in per-wave LDS
    float psum[2][4];
#pragma unroll
    for (int fi = 0; fi < 2; ++fi)
#pragma unroll
      for (int r = 0; r < 4; ++r) {
        float ps = 0.0f;
        int prow = fi * 16 + lhi * 4 + r;
#pragma unroll
        for (int sj = 0; sj < 4; ++sj) {
          float p = __expf(sacc[fi][sj][r] - mrun[fi][r]);
          ps += p;
          Pl[wid][prow * PSTR + sj * 16 + l15] = f2bf(p);
        }
        psum[fi][r] = ps;
      }
#pragma unroll
    for (int d = 1; d < 16; d <<= 1)
#pragma unroll
      for (int fi = 0; fi < 2; ++fi)
#pragma unroll
        for (int r = 0; r < 4; ++r)
          psum[fi][r] += __shfl_xor(psum[fi][r], d, 64);
#pragma unroll
    for (int fi = 0; fi < 2; ++fi)
#pragma unroll
      for (int r = 0; r < 4; ++r) lrun[fi][r] += psum[fi][r];

    // O += P V  (A-op = P from Pl, B-op = V^T from Vt)
#pragma unroll
    for (int kk = 0; kk < 2; ++kk) {
      bf16x8 pf[2], vf[4];
#pragma unroll
      for (int fi = 0; fi < 2; ++fi)
        pf[fi] = *(const bf16x8*)(Pl[wid] + (fi * 16 + l15) * PSTR + kk * 32 + lhi * 8);
#pragma unroll
      for (int dj = 0; dj < 4; ++dj)
        vf[dj] = *(const bf16x8*)(Vt + (dj * 16 + l15) * PSTR + kk * 32 + lhi * 8);
#pragma unroll
      for (int fi = 0; fi < 2; ++fi)
#pragma unroll
        for (int dj = 0; dj < 4; ++dj)
          oacc[fi][dj] = __builtin_amdgcn_mfma_f32_16x16x32_bf16(
              pf[fi], vf[dj], oacc[fi][dj], 0, 0, 0);
    }
  }

  // normalize + store att rows
#pragma unroll
  for (int fi = 0; fi < 2; ++fi)
#pragma unroll
    for (int dj = 0; dj < 4; ++dj)
#pragma unroll
      for (int r = 0; r < 4; ++r) {
        int t = qrow0 + fi * 16 + lhi * 4 + r;
        float v = oacc[fi][dj][r] / lrun[fi][r];
        Og[base + (size_t)t * 1024u + dj * 16 + l15] = f2bf(v);
      }
}

// ---------------------------------------------------------------------------
extern "C" void kernel_launch(void* const* d_in, const int* in_sizes, int n_in,
                              void* d_out, int out_size, void* d_ws, size_t ws_size,
                              hipStream_t stream) {
  const float* x  = (const float*)d_in[0];
  const float* wq = (const float*)d_in[1];
  const float* wk = (const float*)d_in[2];
  const float* wv = (const float*)d_in[3];
  const float* wp = (const float*)d_in[4];
  const float* bp = (const float*)d_in[5];
  float* out = (float*)d_out;

  unsigned short* ws   = (unsigned short*)d_ws;
  unsigned short* x_bf = ws;                          // 8M elems
  unsigned short* wtq  = ws + ((size_t)8 << 20);      // 3M
  unsigned short* wtp  = ws + ((size_t)11 << 20);     // 1M
  unsigned short* qkv  = ws + ((size_t)12 << 20);     // 24M (q,k,v @ 8M stride)
  unsigned short* q    = qkv;
  unsigned short* kk   = qkv + ((size_t)8 << 20);
  unsigned short* vv   = qkv + ((size_t)16 << 20);
  unsigned short* att  = ws + ((size_t)36 << 20);     // 8M

  const int M = 8192, N = 1024, K = 1024;

  cvt_f32_bf16<<<4096, 256, 0, stream>>>(x, x_bf);
  transpose_qkv<<<dim3(16, 16, 3), 256, 0, stream>>>(wq, wk, wv, wtq);
  transpose_proj<<<dim3(16, 16), 256, 0, stream>>>(wp, wtp);
  // q,k,v projections: one dispatch, z selects matrix (out stride 8M elems)
  gemm_bt<0><<<dim3(N / BN, M / BM, 3), 256, 0, stream>>>(x_bf, wtq, nullptr, qkv, M, N, K);
  attn_fwd<<<dim3(16, 64), 256, 0, stream>>>(q, kk, vv, att);
  gemm_bt<1><<<dim3(N / BN, M / BM, 1), 256, 0, stream>>>(att, wtp, bp, out, M, N, K);
}

// Round 3
// 351.502 us; speedup vs baseline: 1.4087x; 1.4087x over previous
//
#include <hip/hip_runtime.h>
#include <stdint.h>

// TimeSeriesAttention: x[B,T,C] -> per-head QKV -> causal softmax(QK^T/32) V -> proj
// B=4 T=2048 C=1024 H=16 D=64.
// Device I/O dtype: float32 (reference dtype). Internal compute: bf16 MFMA.
//
// ws layout (elements of bf16):
//   [0,    8M)  x_bf  [B*T][C]          bf16 copy of x
//   [8M,  11M)  wtq   3 x [n=h*64+d][k] transposed qkv weights (bf16)
//   [11M, 12M)  wtp   [c][k]            transposed proj weight (bf16)
//   [12M, 36M)  q,k,v [B*T][H*D]        each 8M elems
//   [28M, 36M)  att   ALIASES v (v is dead after transpose_v)
//   [36M, 44M)  vt    [B][H][64][2048]  V transposed per head
// total 44M bf16 elems = 88MB of d_ws.

typedef uint32_t u32;
typedef __bf16 bf16x8 __attribute__((ext_vector_type(8)));
typedef unsigned short us8 __attribute__((ext_vector_type(8)));
typedef float f32x4 __attribute__((ext_vector_type(4)));

static __device__ __forceinline__ unsigned short f2bf(float f) {
  union { float f; u32 i; } cv; cv.f = f;
  u32 x = cv.i;
  u32 r = (x + 0x7fffu + ((x >> 16) & 1u)) >> 16;  // RNE
  return (unsigned short)r;
}

// async global->LDS, 16B per lane; LDS dest is wave-uniform base + lane*16.
static __device__ __forceinline__ void gload_lds16(const unsigned short* g, unsigned short* l) {
  __builtin_amdgcn_global_load_lds(
      (__attribute__((address_space(1))) u32*)g,
      (__attribute__((address_space(3))) u32*)l, 16, 0, 0);
}

// ---------------------------------------------------------------------------
// x f32 -> bf16, 8 elems/thread
__global__ __launch_bounds__(256) void cvt_f32_bf16(
    const float* __restrict__ src, unsigned short* __restrict__ dst) {
  size_t i = (size_t)(blockIdx.x * 256 + threadIdx.x) * 8u;
  float4 a = *(const float4*)(src + i);
  float4 b = *(const float4*)(src + i + 4);
  us8 v;
  v[0] = f2bf(a.x); v[1] = f2bf(a.y); v[2] = f2bf(a.z); v[3] = f2bf(a.w);
  v[4] = f2bf(b.x); v[5] = f2bf(b.y); v[6] = f2bf(b.z); v[7] = f2bf(b.w);
  *(us8*)(dst + i) = v;
}

// ---------------------------------------------------------------------------
// wq/wk/wv [H][C][D] f32 -> wt [n=h*64+d][k=c] bf16, via 64x64 LDS tiles.
__global__ __launch_bounds__(256) void transpose_qkv(
    const float* __restrict__ wq, const float* __restrict__ wk,
    const float* __restrict__ wv, unsigned short* __restrict__ dst) {
  __shared__ unsigned short lds[64][66];
  const float* src = (blockIdx.z == 0) ? wq : (blockIdx.z == 1) ? wk : wv;
  unsigned short* d = dst + ((size_t)blockIdx.z << 20);
  const int tid = threadIdx.x;
  const int h = blockIdx.y, c0 = blockIdx.x * 64;
  const float* s = src + (size_t)h * 65536u + (size_t)c0 * 64u;
#pragma unroll
  for (int it = 0; it < 16; ++it) {
    int idx = it * 256 + tid;
    int r = idx >> 6, dd = idx & 63;          // read s[r][dd], coalesced
    lds[dd][r] = f2bf(s[r * 64 + dd]);
  }
  __syncthreads();
#pragma unroll
  for (int it = 0; it < 16; ++it) {
    int idx = it * 256 + tid;
    int dd = idx >> 6, r = idx & 63;          // write row h*64+dd, coalesced
    d[(size_t)(h * 64 + dd) * 1024u + c0 + r] = lds[dd][r];
  }
}

// w_proj [HD=1024][C=1024] f32 -> wtp [c][hd] bf16
__global__ __launch_bounds__(256) void transpose_proj(
    const float* __restrict__ wp, unsigned short* __restrict__ dst) {
  __shared__ unsigned short lds[64][66];
  const int tid = threadIdx.x;
  const int c0 = blockIdx.x * 64, r0 = blockIdx.y * 64;
#pragma unroll
  for (int it = 0; it < 16; ++it) {
    int idx = it * 256 + tid;
    int r = idx >> 6, cc = idx & 63;
    lds[cc][r] = f2bf(wp[(size_t)(r0 + r) * 1024u + c0 + cc]);
  }
  __syncthreads();
#pragma unroll
  for (int it = 0; it < 16; ++it) {
    int idx = it * 256 + tid;
    int cc = idx >> 6, r = idx & 63;
    dst[(size_t)(c0 + cc) * 1024u + r0 + r] = lds[cc][r];
  }
}

// v [B*T][H*64] bf16 -> vt [(b*16+h)*64+d][T=2048] bf16. grid (32 t-tiles, 64 bh)
__global__ __launch_bounds__(256) void transpose_v(
    const unsigned short* __restrict__ v, unsigned short* __restrict__ vt) {
  __shared__ unsigned short lds[64][66];
  const int tid = threadIdx.x;
  const int bh = blockIdx.y, t0 = blockIdx.x * 64;
  const unsigned short* src = v + ((size_t)(bh >> 4) * 2048 + t0) * 1024u + (bh & 15) * 64;
  unsigned short* dst = vt + (size_t)bh * 131072u + t0;
#pragma unroll
  for (int it = 0; it < 16; ++it) {
    int idx = it * 256 + tid;
    int r = idx >> 6, dd = idx & 63;          // read src[t=r][d=dd], coalesced
    lds[dd][r] = src[(size_t)r * 1024u + dd];
  }
  __syncthreads();
#pragma unroll
  for (int it = 0; it < 16; ++it) {
    int idx = it * 256 + tid;
    int dd = idx >> 6, r = idx & 63;          // write dst[d=dd][t=r], coalesced
    dst[(size_t)dd * 2048u + r] = lds[dd][r];
  }
}

// ---------------------------------------------------------------------------
// BT-GEMM: C[m][n] = sum_k A[m][k] * Bt[n][k]  (+ bias[n])
#define BM 128
#define BN 128
#define BK 32

template <int F32OUT>
__global__ __launch_bounds__(256) void gemm_bt(
    const unsigned short* __restrict__ A, const unsigned short* __restrict__ Bt,
    const float* __restrict__ bias, void* __restrict__ Cv,
    int M, int N, int K) {
  __shared__ __align__(16) unsigned short Al[BM * BK];
  __shared__ __align__(16) unsigned short Bl[BN * BK];
  const int tid = threadIdx.x;
  const int wid = tid >> 6, lane = tid & 63;
  const int l15 = lane & 15, lhi = lane >> 4;
  const int m0 = blockIdx.y * BM;
  const int n0 = blockIdx.x * BN;
  const int wr = wid >> 1, wc = wid & 1;
  const unsigned short* Btz = Bt + ((size_t)blockIdx.z << 20);

  f32x4 acc[4][4] = {};

  for (int k0 = 0; k0 < K; k0 += BK) {
#pragma unroll
    for (int j = 0; j < 2; ++j) {
      int q = tid + j * 256;         // chunk id 0..511
      int row = q >> 2, c = q & 3;   // [row][c*8..c*8+7]
      gload_lds16(A + (size_t)(m0 + row) * K + (k0 + c * 8), Al + q * 8);
      gload_lds16(Btz + (size_t)(n0 + row) * K + (k0 + c * 8), Bl + q * 8);
    }
    __syncthreads();
    bf16x8 af[4], bfr[4];
#pragma unroll
    for (int mi = 0; mi < 4; ++mi)
      af[mi] = *(const bf16x8*)(Al + (wr * 64 + mi * 16 + l15) * BK + lhi * 8);
#pragma unroll
    for (int ni = 0; ni < 4; ++ni)
      bfr[ni] = *(const bf16x8*)(Bl + (wc * 64 + ni * 16 + l15) * BK + lhi * 8);
#pragma unroll
    for (int mi = 0; mi < 4; ++mi)
#pragma unroll
      for (int ni = 0; ni < 4; ++ni)
        acc[mi][ni] = __builtin_amdgcn_mfma_f32_16x16x32_bf16(
            af[mi], bfr[ni], acc[mi][ni], 0, 0, 0);
    __syncthreads();
  }
#pragma unroll
  for (int mi = 0; mi < 4; ++mi) {
#pragma unroll
    for (int ni = 0; ni < 4; ++ni) {
      int n = n0 + wc * 64 + ni * 16 + l15;
      if constexpr (F32OUT) {
        float* Cz = (float*)Cv;
        float badd = bias[n];
#pragma unroll
        for (int r = 0; r < 4; ++r) {
          int m = m0 + wr * 64 + mi * 16 + lhi * 4 + r;
          Cz[(size_t)m * N + n] = acc[mi][ni][r] + badd;
        }
      } else {
        unsigned short* Cz = (unsigned short*)Cv + ((size_t)blockIdx.z << 23);
#pragma unroll
        for (int r = 0; r < 4; ++r) {
          int m = m0 + wr * 64 + mi * 16 + lhi * 4 + r;
          Cz[(size_t)m * N + n] = f2bf(acc[mi][ni][r]);
        }
      }
    }
  }
}

// ---------------------------------------------------------------------------
// Flash causal attention. One block = (b,h,q-tile of 128). 4 waves x 32 rows.
// KV tile 64. K and V^T staged via global_load_lds into linear LDS with
// XOR-chunk swizzle (c ^= r&7 on BOTH global source and ds_read side).
// Double-buffered, ONE __syncthreads per tile (loads for tile kt+1 issued
// before compute of tile kt; the end-of-iter barrier's vmcnt drain lands
// after a full compute phase of overlap).
#define QT 128
#define KVT 64
#define PSTR 72

__global__ __launch_bounds__(256) void attn_fwd(
    const unsigned short* __restrict__ Qg, const unsigned short* __restrict__ Kg,
    const unsigned short* __restrict__ Vtg, unsigned short* __restrict__ Og) {
  __shared__ __align__(16) unsigned short Kl[2][64 * 64];
  __shared__ __align__(16) unsigned short Vl[2][64 * 64];
  __shared__ __align__(16) unsigned short Pl[4][32 * PSTR];
  const int tid = threadIdx.x, wid = tid >> 6, lane = tid & 63;
  const int l15 = lane & 15, lhi = lane >> 4, x7 = lane & 7;
  const int qt = 15 - blockIdx.x;   // descending work: big blocks launch first
  const size_t base = (size_t)(blockIdx.y >> 4) * (2048u * 1024u) +
                      (size_t)(blockIdx.y & 15) * 64u;
  const size_t vtbase = (size_t)blockIdx.y * (64u * 2048u);
  const int qrow0 = qt * QT + wid * 32;

  auto stage = [&](int bufi, int s0) {
#pragma unroll
    for (int j = 0; j < 2; ++j) {
      int q = tid + j * 256;                 // 512 chunks of 16B per matrix
      int r = q >> 3;                        // row (s for K, d for Vt)
      int c = (q & 7) ^ (r & 7);             // inverse-swizzled source chunk
      gload_lds16(Kg + base + (size_t)(s0 + r) * 1024u + c * 8, &Kl[bufi][q * 8]);
      gload_lds16(Vtg + vtbase + (size_t)r * 2048u + s0 + c * 8, &Vl[bufi][q * 8]);
    }
  };

  // Q fragments in registers: rows qrow0..+31
  bf16x8 qf[2][2];
#pragma unroll
  for (int fi = 0; fi < 2; ++fi)
#pragma unroll
    for (int kj = 0; kj < 2; ++kj)
      qf[fi][kj] = *(const bf16x8*)(Qg + base +
          (size_t)(qrow0 + fi * 16 + l15) * 1024u + kj * 32 + lhi * 8);

  float mrun[2][4], lrun[2][4];
  f32x4 oacc[2][4] = {};
#pragma unroll
  for (int fi = 0; fi < 2; ++fi)
#pragma unroll
    for (int r = 0; r < 4; ++r) { mrun[fi][r] = -1e30f; lrun[fi][r] = 0.0f; }

  const int ntiles = 2 * (qt + 1);  // causal
  stage(0, 0);
  __syncthreads();

  for (int kt = 0; kt < ntiles; ++kt) {
    const int cur = kt & 1;
    const int s0 = kt * KVT;
    if (kt + 1 < ntiles) stage(cur ^ 1, s0 + KVT);
    const unsigned short* Kb = Kl[cur];
    const unsigned short* Vb = Vl[cur];

    // S = Q K^T
    f32x4 sacc[2][4] = {};
#pragma unroll
    for (int kj = 0; kj < 2; ++kj) {
      bf16x8 kf[4];
#pragma unroll
      for (int sj = 0; sj < 4; ++sj) {
        int r = sj * 16 + l15;
        kf[sj] = *(const bf16x8*)(&Kb[r * 64 + (((kj * 4 + lhi) ^ x7) * 8)]);
      }
#pragma unroll
      for (int fi = 0; fi < 2; ++fi)
#pragma unroll
        for (int sj = 0; sj < 4; ++sj)
          sacc[fi][sj] = __builtin_amdgcn_mfma_f32_16x16x32_bf16(
              qf[fi][kj], kf[sj], sacc[fi][sj], 0, 0, 0);
    }

    // scale 1/32, causal mask, per-row tile max
    float tmax[2][4];
#pragma unroll
    for (int fi = 0; fi < 2; ++fi)
#pragma unroll
      for (int r = 0; r < 4; ++r) {
        int row = qrow0 + fi * 16 + lhi * 4 + r;
        float mx = -1e30f;
#pragma unroll
        for (int sj = 0; sj < 4; ++sj) {
          int col = s0 + sj * 16 + l15;
          float v = sacc[fi][sj][r] * 0.03125f;
          v = (col <= row) ? v : -1e30f;
          sacc[fi][sj][r] = v;
          mx = fmaxf(mx, v);
        }
        tmax[fi][r] = mx;
      }
#pragma unroll
    for (int d = 1; d < 16; d <<= 1)
#pragma unroll
      for (int fi = 0; fi < 2; ++fi)
#pragma unroll
        for (int r = 0; r < 4; ++r)
          tmax[fi][r] = fmaxf(tmax[fi][r], __shfl_xor(tmax[fi][r], d, 64));

    // online-softmax rescale
    float sc[2][4];
#pragma unroll
    for (int fi = 0; fi < 2; ++fi)
#pragma unroll
      for (int r = 0; r < 4; ++r) {
        float mnew = fmaxf(mrun[fi][r], tmax[fi][r]);
        sc[fi][r] = __expf(mrun[fi][r] - mnew);
        mrun[fi][r] = mnew;
        lrun[fi][r] *= sc[fi][r];
      }
#pragma unroll
    for (int fi = 0; fi < 2; ++fi)
#pragma unroll
      for (int dj = 0; dj < 4; ++dj)
#pragma unroll
        for (int r = 0; r < 4; ++r)
          oacc[fi][dj][r] *= sc[fi][r];

    // P = exp(S - m), row-sum, stash P (bf16) in per-wave LDS
    float psum[2][4];
#pragma unroll
    for (int fi = 0; fi < 2; ++fi)
#pragma unroll
      for (int r = 0; r < 4; ++r) {
        float ps = 0.0f;
        int prow = fi * 16 + lhi * 4 + r;
#pragma unroll
        for (int sj = 0; sj < 4; ++sj) {
          float p = __expf(sacc[fi][sj][r] - mrun[fi][r]);
          ps += p;
          Pl[wid][prow * PSTR + sj * 16 + l15] = f2bf(p);
        }
        psum[fi][r] = ps;
      }
#pragma unroll
    for (int d = 1; d < 16; d <<= 1)
#pragma unroll
      for (int fi = 0; fi < 2; ++fi)
#pragma unroll
        for (int r = 0; r < 4; ++r)
          psum[fi][r] += __shfl_xor(psum[fi][r], d, 64);
#pragma unroll
    for (int fi = 0; fi < 2; ++fi)
#pragma unroll
      for (int r = 0; r < 4; ++r) lrun[fi][r] += psum[fi][r];

    // O += P V  (A-op = P from Pl, B-op = V^T rows from Vl)
#pragma unroll
    for (int kk = 0; kk < 2; ++kk) {
      bf16x8 pf[2], vf[4];
#pragma unroll
      for (int fi = 0; fi < 2; ++fi)
        pf[fi] = *(const bf16x8*)(&Pl[wid][(fi * 16 + l15) * PSTR + kk * 32 + lhi * 8]);
#pragma unroll
      for (int dj = 0; dj < 4; ++dj) {
        int r = dj * 16 + l15;
        vf[dj] = *(const bf16x8*)(&Vb[r * 64 + (((kk * 4 + lhi) ^ x7) * 8)]);
      }
#pragma unroll
      for (int fi = 0; fi < 2; ++fi)
#pragma unroll
        for (int dj = 0; dj < 4; ++dj)
          oacc[fi][dj] = __builtin_amdgcn_mfma_f32_16x16x32_bf16(
              pf[fi], vf[dj], oacc[fi][dj], 0, 0, 0);
    }

    __syncthreads();  // all reads of buf[cur] done; drains next-tile loads
  }

  // normalize + store att rows
#pragma unroll
  for (int fi = 0; fi < 2; ++fi)
#pragma unroll
    for (int dj = 0; dj < 4; ++dj)
#pragma unroll
      for (int r = 0; r < 4; ++r) {
        int t = qrow0 + fi * 16 + lhi * 4 + r;
        float v = oacc[fi][dj][r] / lrun[fi][r];
        Og[base + (size_t)t * 1024u + dj * 16 + l15] = f2bf(v);
      }
}

// ---------------------------------------------------------------------------
extern "C" void kernel_launch(void* const* d_in, const int* in_sizes, int n_in,
                              void* d_out, int out_size, void* d_ws, size_t ws_size,
                              hipStream_t stream) {
  const float* x  = (const float*)d_in[0];
  const float* wq = (const float*)d_in[1];
  const float* wk = (const float*)d_in[2];
  const float* wv = (const float*)d_in[3];
  const float* wp = (const float*)d_in[4];
  const float* bp = (const float*)d_in[5];
  float* out = (float*)d_out;

  unsigned short* ws   = (unsigned short*)d_ws;
  unsigned short* x_bf = ws;                          // 8M elems
  unsigned short* wtq  = ws + ((size_t)8 << 20);      // 3M
  unsigned short* wtp  = ws + ((size_t)11 << 20);     // 1M
  unsigned short* qkv  = ws + ((size_t)12 << 20);     // 24M (q,k,v @ 8M stride)
  unsigned short* q    = qkv;
  unsigned short* kk   = qkv + ((size_t)8 << 20);
  unsigned short* vv   = qkv + ((size_t)16 << 20);
  unsigned short* att  = vv;                          // alias: v dead after transpose_v
  unsigned short* vt   = ws + ((size_t)36 << 20);     // 8M

  const int M = 8192, N = 1024, K = 1024;

  cvt_f32_bf16<<<4096, 256, 0, stream>>>(x, x_bf);
  transpose_qkv<<<dim3(16, 16, 3), 256, 0, stream>>>(wq, wk, wv, wtq);
  transpose_proj<<<dim3(16, 16), 256, 0, stream>>>(wp, wtp);
  gemm_bt<0><<<dim3(N / BN, M / BM, 3), 256, 0, stream>>>(x_bf, wtq, nullptr, qkv, M, N, K);
  transpose_v<<<dim3(32, 64), 256, 0, stream>>>(vv, vt);
  attn_fwd<<<dim3(16, 64), 256, 0, stream>>>(q, kk, vt, att);
  gemm_bt<1><<<dim3(N / BN, M / BM, 1), 256, 0, stream>>>(att, wtp, bp, out, M, N, K);
}

// Round 5
// 269.498 us; speedup vs baseline: 1.8373x; 1.3043x over previous
//
#include <hip/hip_runtime.h>
#include <stdint.h>

// TimeSeriesAttention: x[B,T,C] -> per-head QKV -> causal softmax(QK^T/32) V -> proj
// B=4 T=2048 C=1024 H=16 D=64.
// Device I/O dtype: float32 (reference dtype). Internal compute: bf16 MFMA.
//
// ws layout (elements of bf16):
//   [0,    8M)  x_bf  [B*T][C]          bf16 copy of x
//   [8M,  11M)  wtq   3 x [n=h*64+d][k] transposed qkv weights (bf16)
//   [11M, 12M)  wtp   [c][k]            transposed proj weight (bf16)
//   [12M, 36M)  q,k,v [B*T][H*D]        each 8M elems
//   [28M, 36M)  att   ALIASES v (v is dead after transpose_v)
//   [36M, 44M)  vt    [B][H][64][2048]  V transposed per head
// total 44M bf16 elems = 88MB of d_ws.

typedef uint32_t u32;
typedef __bf16 bf16x8 __attribute__((ext_vector_type(8)));
typedef unsigned short us8 __attribute__((ext_vector_type(8)));
typedef float f32x4 __attribute__((ext_vector_type(4)));

#define EXP2F(x) __builtin_amdgcn_exp2f(x)   // v_exp_f32 (2^x)

static __device__ __forceinline__ unsigned short f2bf(float f) {
  union { float f; u32 i; } cv; cv.f = f;
  u32 x = cv.i;
  u32 r = (x + 0x7fffu + ((x >> 16) & 1u)) >> 16;  // RNE
  return (unsigned short)r;
}

// async global->LDS, 16B per lane; LDS dest is wave-uniform base + lane*16.
static __device__ __forceinline__ void gload_lds16(const unsigned short* g, unsigned short* l) {
  __builtin_amdgcn_global_load_lds(
      (__attribute__((address_space(1))) u32*)g,
      (__attribute__((address_space(3))) u32*)l, 16, 0, 0);
}

// ---------------------------------------------------------------------------
// x f32 -> bf16, 8 elems/thread
__global__ __launch_bounds__(256) void cvt_f32_bf16(
    const float* __restrict__ src, unsigned short* __restrict__ dst) {
  size_t i = (size_t)(blockIdx.x * 256 + threadIdx.x) * 8u;
  float4 a = *(const float4*)(src + i);
  float4 b = *(const float4*)(src + i + 4);
  us8 v;
  v[0] = f2bf(a.x); v[1] = f2bf(a.y); v[2] = f2bf(a.z); v[3] = f2bf(a.w);
  v[4] = f2bf(b.x); v[5] = f2bf(b.y); v[6] = f2bf(b.z); v[7] = f2bf(b.w);
  *(us8*)(dst + i) = v;
}

// ---------------------------------------------------------------------------
// wq/wk/wv [H][C][D] f32 -> wt [n=h*64+d][k=c] bf16, via 64x64 LDS tiles.
__global__ __launch_bounds__(256) void transpose_qkv(
    const float* __restrict__ wq, const float* __restrict__ wk,
    const float* __restrict__ wv, unsigned short* __restrict__ dst) {
  __shared__ unsigned short lds[64][66];
  const float* src = (blockIdx.z == 0) ? wq : (blockIdx.z == 1) ? wk : wv;
  unsigned short* d = dst + ((size_t)blockIdx.z << 20);
  const int tid = threadIdx.x;
  const int h = blockIdx.y, c0 = blockIdx.x * 64;
  const float* s = src + (size_t)h * 65536u + (size_t)c0 * 64u;
#pragma unroll
  for (int it = 0; it < 16; ++it) {
    int idx = it * 256 + tid;
    int r = idx >> 6, dd = idx & 63;          // read s[r][dd], coalesced
    lds[dd][r] = f2bf(s[r * 64 + dd]);
  }
  __syncthreads();
#pragma unroll
  for (int it = 0; it < 16; ++it) {
    int idx = it * 256 + tid;
    int dd = idx >> 6, r = idx & 63;          // write row h*64+dd, coalesced
    d[(size_t)(h * 64 + dd) * 1024u + c0 + r] = lds[dd][r];
  }
}

// w_proj [HD=1024][C=1024] f32 -> wtp [c][hd] bf16
__global__ __launch_bounds__(256) void transpose_proj(
    const float* __restrict__ wp, unsigned short* __restrict__ dst) {
  __shared__ unsigned short lds[64][66];
  const int tid = threadIdx.x;
  const int c0 = blockIdx.x * 64, r0 = blockIdx.y * 64;
#pragma unroll
  for (int it = 0; it < 16; ++it) {
    int idx = it * 256 + tid;
    int r = idx >> 6, cc = idx & 63;
    lds[cc][r] = f2bf(wp[(size_t)(r0 + r) * 1024u + c0 + cc]);
  }
  __syncthreads();
#pragma unroll
  for (int it = 0; it < 16; ++it) {
    int idx = it * 256 + tid;
    int cc = idx >> 6, r = idx & 63;
    dst[(size_t)(c0 + cc) * 1024u + r0 + r] = lds[cc][r];
  }
}

// v [B*T][H*64] bf16 -> vt [(b*16+h)*64+d][T=2048] bf16. grid (32 t-tiles, 64 bh)
__global__ __launch_bounds__(256) void transpose_v(
    const unsigned short* __restrict__ v, unsigned short* __restrict__ vt) {
  __shared__ unsigned short lds[64][66];
  const int tid = threadIdx.x;
  const int bh = blockIdx.y, t0 = blockIdx.x * 64;
  const unsigned short* src = v + ((size_t)(bh >> 4) * 2048 + t0) * 1024u + (bh & 15) * 64;
  unsigned short* dst = vt + (size_t)bh * 131072u + t0;
#pragma unroll
  for (int it = 0; it < 16; ++it) {
    int idx = it * 256 + tid;
    int r = idx >> 6, dd = idx & 63;          // read src[t=r][d=dd], coalesced
    lds[dd][r] = src[(size_t)r * 1024u + dd];
  }
  __syncthreads();
#pragma unroll
  for (int it = 0; it < 16; ++it) {
    int idx = it * 256 + tid;
    int dd = idx >> 6, r = idx & 63;          // write dst[d=dd][t=r], coalesced
    dst[(size_t)dd * 2048u + r] = lds[dd][r];
  }
}

// ---------------------------------------------------------------------------
// BT-GEMM: C[m][n] = sum_k A[m][k] * Bt[n][k]  (+ bias[n])
#define BM 128
#define BN 128
#define BK 32

template <int F32OUT>
__global__ __launch_bounds__(256) void gemm_bt(
    const unsigned short* __restrict__ A, const unsigned short* __restrict__ Bt,
    const float* __restrict__ bias, void* __restrict__ Cv,
    int M, int N, int K) {
  __shared__ __align__(16) unsigned short Al[BM * BK];
  __shared__ __align__(16) unsigned short Bl[BN * BK];
  const int tid = threadIdx.x;
  const int wid = tid >> 6, lane = tid & 63;
  const int l15 = lane & 15, lhi = lane >> 4;
  const int m0 = blockIdx.y * BM;
  const int n0 = blockIdx.x * BN;
  const int wr = wid >> 1, wc = wid & 1;
  const unsigned short* Btz = Bt + ((size_t)blockIdx.z << 20);

  f32x4 acc[4][4] = {};

  for (int k0 = 0; k0 < K; k0 += BK) {
#pragma unroll
    for (int j = 0; j < 2; ++j) {
      int q = tid + j * 256;         // chunk id 0..511
      int row = q >> 2, c = q & 3;   // [row][c*8..c*8+7]
      gload_lds16(A + (size_t)(m0 + row) * K + (k0 + c * 8), Al + q * 8);
      gload_lds16(Btz + (size_t)(n0 + row) * K + (k0 + c * 8), Bl + q * 8);
    }
    __syncthreads();
    bf16x8 af[4], bfr[4];
#pragma unroll
    for (int mi = 0; mi < 4; ++mi)
      af[mi] = *(const bf16x8*)(Al + (wr * 64 + mi * 16 + l15) * BK + lhi * 8);
#pragma unroll
    for (int ni = 0; ni < 4; ++ni)
      bfr[ni] = *(const bf16x8*)(Bl + (wc * 64 + ni * 16 + l15) * BK + lhi * 8);
#pragma unroll
    for (int mi = 0; mi < 4; ++mi)
#pragma unroll
      for (int ni = 0; ni < 4; ++ni)
        acc[mi][ni] = __builtin_amdgcn_mfma_f32_16x16x32_bf16(
            af[mi], bfr[ni], acc[mi][ni], 0, 0, 0);
    __syncthreads();
  }
#pragma unroll
  for (int mi = 0; mi < 4; ++mi) {
#pragma unroll
    for (int ni = 0; ni < 4; ++ni) {
      int n = n0 + wc * 64 + ni * 16 + l15;
      if constexpr (F32OUT) {
        float* Cz = (float*)Cv;
        float badd = bias[n];
#pragma unroll
        for (int r = 0; r < 4; ++r) {
          int m = m0 + wr * 64 + mi * 16 + lhi * 4 + r;
          Cz[(size_t)m * N + n] = acc[mi][ni][r] + badd;
        }
      } else {
        unsigned short* Cz = (unsigned short*)Cv + ((size_t)blockIdx.z << 23);
#pragma unroll
        for (int r = 0; r < 4; ++r) {
          int m = m0 + wr * 64 + mi * 16 + lhi * 4 + r;
          Cz[(size_t)m * N + n] = f2bf(acc[mi][ni][r]);
        }
      }
    }
  }
}

// ---------------------------------------------------------------------------
// Flash causal attention. One block = (b,h, q-tile PAIR {qt, 15-qt}) so every
// block does exactly 2(qt+1)+2(16-qt)=34 KV-tiles -> perfect load balance,
// 512 blocks = 2 blocks/CU all resident. 4 waves x 32 q-rows. KV tile 64.
// K and V^T staged via global_load_lds, XOR-chunk swizzle both sides.
// Double-buffered, ONE barrier per tile; pipeline continues across the pair
// boundary. Unscaled S tracked; softmax via exp2 with folded 1/32*log2(e).
#define QT 128
#define KVT 64
#define PSTR 72
#define SCLOG2E 0.04508422f  // (1/32) * log2(e)

__global__ __launch_bounds__(256) void attn_fwd(
    const unsigned short* __restrict__ Qg, const unsigned short* __restrict__ Kg,
    const unsigned short* __restrict__ Vtg, unsigned short* __restrict__ Og) {
  __shared__ __align__(16) unsigned short Kl[2][64 * 64];
  __shared__ __align__(16) unsigned short Vl[2][64 * 64];
  __shared__ __align__(16) unsigned short Pl[4][32 * PSTR];
  const int tid = threadIdx.x, wid = tid >> 6, lane = tid & 63;
  const int l15 = lane & 15, lhi = lane >> 4, x7 = lane & 7;
  const size_t base = (size_t)(blockIdx.y >> 4) * (2048u * 1024u) +
                      (size_t)(blockIdx.y & 15) * 64u;
  const size_t vtbase = (size_t)blockIdx.y * (64u * 2048u);
  const int qtA = blockIdx.x, qtB = 15 - qtA;
  const int n0 = 2 * (qtA + 1), n1 = 2 * (qtB + 1);
  const int ntot = n0 + n1;  // 34 for every block

  auto s0_of = [&](int g) { return ((g < n0) ? g : g - n0) * KVT; };

  auto stage = [&](int bufi, int s0) {
#pragma unroll
    for (int j = 0; j < 2; ++j) {
      int q = tid + j * 256;                 // 512 chunks of 16B per matrix
      int r = q >> 3;                        // row (s for K, d for Vt)
      int c = (q & 7) ^ (r & 7);             // inverse-swizzled source chunk
      gload_lds16(Kg + base + (size_t)(s0 + r) * 1024u + c * 8, &Kl[bufi][q * 8]);
      gload_lds16(Vtg + vtbase + (size_t)r * 2048u + s0 + c * 8, &Vl[bufi][q * 8]);
    }
  };

  stage(0, 0);
  __syncthreads();

  int g = 0;
  for (int pass = 0; pass < 2; ++pass) {
    const int qt = pass ? qtB : qtA;
    const int nt = pass ? n1 : n0;
    const int qrow0 = qt * QT + wid * 32;

    // Q fragments in registers: rows qrow0..+31
    bf16x8 qf[2][2];
#pragma unroll
    for (int fi = 0; fi < 2; ++fi)
#pragma unroll
      for (int kj = 0; kj < 2; ++kj)
        qf[fi][kj] = *(const bf16x8*)(Qg + base +
            (size_t)(qrow0 + fi * 16 + l15) * 1024u + kj * 32 + lhi * 8);

    float mrun[2][4], lrun[2][4];
    f32x4 oacc[2][4] = {};
#pragma unroll
    for (int fi = 0; fi < 2; ++fi)
#pragma unroll
      for (int r = 0; r < 4; ++r) { mrun[fi][r] = -1e30f; lrun[fi][r] = 0.0f; }

    for (int kt = 0; kt < nt; ++kt, ++g) {
      const int cur = g & 1;
      const int s0 = kt * KVT;
      if (g + 1 < ntot) stage(cur ^ 1, s0_of(g + 1));
      // wave-uniform: skip tiles fully above the causal diagonal for our rows
      if (s0 <= qrow0 + 31) {
        const bool notfull = (s0 + KVT - 1 > qrow0);  // needs masking
        const unsigned short* Kb = Kl[cur];
        const unsigned short* Vb = Vl[cur];

        // S = Q K^T (unscaled)
        f32x4 sacc[2][4] = {};
#pragma unroll
        for (int kj = 0; kj < 2; ++kj) {
          bf16x8 kf[4];
#pragma unroll
          for (int sj = 0; sj < 4; ++sj) {
            int r = sj * 16 + l15;
            kf[sj] = *(const bf16x8*)(&Kb[r * 64 + (((kj * 4 + lhi) ^ x7) * 8)]);
          }
#pragma unroll
          for (int fi = 0; fi < 2; ++fi)
#pragma unroll
            for (int sj = 0; sj < 4; ++sj)
              sacc[fi][sj] = __builtin_amdgcn_mfma_f32_16x16x32_bf16(
                  qf[fi][kj], kf[sj], sacc[fi][sj], 0, 0, 0);
        }

        // causal mask (only near-diagonal tiles), per-row tile max
        float tmax[2][4];
#pragma unroll
        for (int fi = 0; fi < 2; ++fi)
#pragma unroll
          for (int r = 0; r < 4; ++r) {
            int row = qrow0 + fi * 16 + lhi * 4 + r;
            float mx = -3e38f;
#pragma unroll
            for (int sj = 0; sj < 4; ++sj) {
              float v = sacc[fi][sj][r];
              if (notfull) {
                int col = s0 + sj * 16 + l15;
                v = (col <= row) ? v : -3e38f;
                sacc[fi][sj][r] = v;
              }
              mx = fmaxf(mx, v);
            }
            tmax[fi][r] = mx;
          }
#pragma unroll
        for (int d = 1; d < 16; d <<= 1)
#pragma unroll
          for (int fi = 0; fi < 2; ++fi)
#pragma unroll
            for (int r = 0; r < 4; ++r)
              tmax[fi][r] = fmaxf(tmax[fi][r], __shfl_xor(tmax[fi][r], d, 64));

        // online-softmax rescale (units: unscaled S; exp2 with folded const)
        float sc[2][4];
#pragma unroll
        for (int fi = 0; fi < 2; ++fi)
#pragma unroll
          for (int r = 0; r < 4; ++r) {
            float mnew = fmaxf(mrun[fi][r], tmax[fi][r]);
            sc[fi][r] = EXP2F((mrun[fi][r] - mnew) * SCLOG2E);
            mrun[fi][r] = mnew;
            lrun[fi][r] *= sc[fi][r];
          }
#pragma unroll
        for (int fi = 0; fi < 2; ++fi)
#pragma unroll
          for (int dj = 0; dj < 4; ++dj)
#pragma unroll
            for (int r = 0; r < 4; ++r)
              oacc[fi][dj][r] *= sc[fi][r];

        // P = exp2((S-m)*C), row-sum, stash P (bf16) in per-wave LDS
        float psum[2][4];
#pragma unroll
        for (int fi = 0; fi < 2; ++fi)
#pragma unroll
          for (int r = 0; r < 4; ++r) {
            float ps = 0.0f;
            int prow = fi * 16 + lhi * 4 + r;
#pragma unroll
            for (int sj = 0; sj < 4; ++sj) {
              float p = EXP2F((sacc[fi][sj][r] - mrun[fi][r]) * SCLOG2E);
              ps += p;
              Pl[wid][prow * PSTR + sj * 16 + l15] = f2bf(p);
            }
            psum[fi][r] = ps;
          }
#pragma unroll
        for (int d = 1; d < 16; d <<= 1)
#pragma unroll
          for (int fi = 0; fi < 2; ++fi)
#pragma unroll
            for (int r = 0; r < 4; ++r)
              psum[fi][r] += __shfl_xor(psum[fi][r], d, 64);
#pragma unroll
        for (int fi = 0; fi < 2; ++fi)
#pragma unroll
          for (int r = 0; r < 4; ++r) lrun[fi][r] += psum[fi][r];

        // O += P V  (A-op = P from Pl, B-op = V^T rows from Vl)
#pragma unroll
        for (int kk = 0; kk < 2; ++kk) {
          bf16x8 pf[2], vf[4];
#pragma unroll
          for (int fi = 0; fi < 2; ++fi)
            pf[fi] = *(const bf16x8*)(&Pl[wid][(fi * 16 + l15) * PSTR + kk * 32 + lhi * 8]);
#pragma unroll
          for (int dj = 0; dj < 4; ++dj) {
            int r = dj * 16 + l15;
            vf[dj] = *(const bf16x8*)(&Vb[r * 64 + (((kk * 4 + lhi) ^ x7) * 8)]);
          }
#pragma unroll
          for (int fi = 0; fi < 2; ++fi)
#pragma unroll
            for (int dj = 0; dj < 4; ++dj)
              oacc[fi][dj] = __builtin_amdgcn_mfma_f32_16x16x32_bf16(
                  pf[fi], vf[dj], oacc[fi][dj], 0, 0, 0);
        }
      }

      __syncthreads();  // all reads of buf[cur] done; drains next-tile loads
    }

    // normalize + store this q-tile's rows
#pragma unroll
    for (int fi = 0; fi < 2; ++fi)
#pragma unroll
      for (int dj = 0; dj < 4; ++dj)
#pragma unroll
        for (int r = 0; r < 4; ++r) {
          int t = qrow0 + fi * 16 + lhi * 4 + r;
          float v = oacc[fi][dj][r] / lrun[fi][r];
          Og[base + (size_t)t * 1024u + dj * 16 + l15] = f2bf(v);
        }
  }
}

// ---------------------------------------------------------------------------
extern "C" void kernel_launch(void* const* d_in, const int* in_sizes, int n_in,
                              void* d_out, int out_size, void* d_ws, size_t ws_size,
                              hipStream_t stream) {
  const float* x  = (const float*)d_in[0];
  const float* wq = (const float*)d_in[1];
  const float* wk = (const float*)d_in[2];
  const float* wv = (const float*)d_in[3];
  const float* wp = (const float*)d_in[4];
  const float* bp = (const float*)d_in[5];
  float* out = (float*)d_out;

  unsigned short* ws   = (unsigned short*)d_ws;
  unsigned short* x_bf = ws;                          // 8M elems
  unsigned short* wtq  = ws + ((size_t)8 << 20);      // 3M
  unsigned short* wtp  = ws + ((size_t)11 << 20);     // 1M
  unsigned short* qkv  = ws + ((size_t)12 << 20);     // 24M (q,k,v @ 8M stride)
  unsigned short* q    = qkv;
  unsigned short* kk   = qkv + ((size_t)8 << 20);
  unsigned short* vv   = qkv + ((size_t)16 << 20);
  unsigned short* att  = vv;                          // alias: v dead after transpose_v
  unsigned short* vt   = ws + ((size_t)36 << 20);     // 8M

  const int M = 8192, N = 1024, K = 1024;

  cvt_f32_bf16<<<4096, 256, 0, stream>>>(x, x_bf);
  transpose_qkv<<<dim3(16, 16, 3), 256, 0, stream>>>(wq, wk, wv, wtq);
  transpose_proj<<<dim3(16, 16), 256, 0, stream>>>(wp, wtp);
  gemm_bt<0><<<dim3(N / BN, M / BM, 3), 256, 0, stream>>>(x_bf, wtq, nullptr, qkv, M, N, K);
  transpose_v<<<dim3(32, 64), 256, 0, stream>>>(vv, vt);
  attn_fwd<<<dim3(8, 64), 256, 0, stream>>>(q, kk, vt, att);
  gemm_bt<1><<<dim3(N / BN, M / BM, 1), 256, 0, stream>>>(att, wtp, bp, out, M, N, K);
}

// Round 6
// 210.232 us; speedup vs baseline: 2.3553x; 1.2819x over previous
//
#include <hip/hip_runtime.h>
#include <stdint.h>

// TimeSeriesAttention: x[B,T,C] -> per-head QKV -> causal softmax(QK^T/32) V -> proj
// B=4 T=2048 C=1024 H=16 D=64.
// Device I/O dtype: float32 (reference dtype). Internal compute: bf16 MFMA.
//
// ws layout (elements of bf16):
//   [0,    8M)  x_bf  [B*T][C]          bf16 copy of x
//   [8M,  11M)  wtq   3 x [n=h*64+d][k] transposed qkv weights (bf16)
//   [11M, 12M)  wtp   [c][k]            transposed proj weight (bf16)
//   [12M, 36M)  q,k,v [B*T][H*D]        each 8M elems
//   [28M, 36M)  att   ALIASES v (v is dead after transpose_v)
//   [36M, 44M)  vt    [B][H][64][2048]  V transposed per head
// total 44M bf16 elems = 88MB of d_ws.

typedef uint32_t u32;
typedef __bf16 bf16x8 __attribute__((ext_vector_type(8)));
typedef __bf16 bf16x4 __attribute__((ext_vector_type(4)));
typedef unsigned short us8 __attribute__((ext_vector_type(8)));
typedef float f32x4 __attribute__((ext_vector_type(4)));

#define EXP2F(x) __builtin_amdgcn_exp2f(x)   // v_exp_f32 (2^x)

static __device__ __forceinline__ unsigned short f2bf(float f) {
  union { float f; u32 i; } cv; cv.f = f;
  u32 x = cv.i;
  u32 r = (x + 0x7fffu + ((x >> 16) & 1u)) >> 16;  // RNE
  return (unsigned short)r;
}

// async global->LDS, 16B per lane; LDS dest is wave-uniform base + lane*16.
static __device__ __forceinline__ void gload_lds16(const unsigned short* g, unsigned short* l) {
  __builtin_amdgcn_global_load_lds(
      (__attribute__((address_space(1))) u32*)g,
      (__attribute__((address_space(3))) u32*)l, 16, 0, 0);
}

// ---------------------------------------------------------------------------
// x f32 -> bf16, 8 elems/thread
__global__ __launch_bounds__(256) void cvt_f32_bf16(
    const float* __restrict__ src, unsigned short* __restrict__ dst) {
  size_t i = (size_t)(blockIdx.x * 256 + threadIdx.x) * 8u;
  float4 a = *(const float4*)(src + i);
  float4 b = *(const float4*)(src + i + 4);
  us8 v;
  v[0] = f2bf(a.x); v[1] = f2bf(a.y); v[2] = f2bf(a.z); v[3] = f2bf(a.w);
  v[4] = f2bf(b.x); v[5] = f2bf(b.y); v[6] = f2bf(b.z); v[7] = f2bf(b.w);
  *(us8*)(dst + i) = v;
}

// ---------------------------------------------------------------------------
// wq/wk/wv [H][C][D] f32 -> wt [n=h*64+d][k=c] bf16, via 64x64 LDS tiles.
__global__ __launch_bounds__(256) void transpose_qkv(
    const float* __restrict__ wq, const float* __restrict__ wk,
    const float* __restrict__ wv, unsigned short* __restrict__ dst) {
  __shared__ unsigned short lds[64][66];
  const float* src = (blockIdx.z == 0) ? wq : (blockIdx.z == 1) ? wk : wv;
  unsigned short* d = dst + ((size_t)blockIdx.z << 20);
  const int tid = threadIdx.x;
  const int h = blockIdx.y, c0 = blockIdx.x * 64;
  const float* s = src + (size_t)h * 65536u + (size_t)c0 * 64u;
#pragma unroll
  for (int it = 0; it < 16; ++it) {
    int idx = it * 256 + tid;
    int r = idx >> 6, dd = idx & 63;          // read s[r][dd], coalesced
    lds[dd][r] = f2bf(s[r * 64 + dd]);
  }
  __syncthreads();
#pragma unroll
  for (int it = 0; it < 16; ++it) {
    int idx = it * 256 + tid;
    int dd = idx >> 6, r = idx & 63;          // write row h*64+dd, coalesced
    d[(size_t)(h * 64 + dd) * 1024u + c0 + r] = lds[dd][r];
  }
}

// w_proj [HD=1024][C=1024] f32 -> wtp [c][hd] bf16
__global__ __launch_bounds__(256) void transpose_proj(
    const float* __restrict__ wp, unsigned short* __restrict__ dst) {
  __shared__ unsigned short lds[64][66];
  const int tid = threadIdx.x;
  const int c0 = blockIdx.x * 64, r0 = blockIdx.y * 64;
#pragma unroll
  for (int it = 0; it < 16; ++it) {
    int idx = it * 256 + tid;
    int r = idx >> 6, cc = idx & 63;
    lds[cc][r] = f2bf(wp[(size_t)(r0 + r) * 1024u + c0 + cc]);
  }
  __syncthreads();
#pragma unroll
  for (int it = 0; it < 16; ++it) {
    int idx = it * 256 + tid;
    int cc = idx >> 6, r = idx & 63;
    dst[(size_t)(c0 + cc) * 1024u + r0 + r] = lds[cc][r];
  }
}

// v [B*T][H*64] bf16 -> vt [(b*16+h)*64+d][T=2048] bf16. grid (32 t-tiles, 64 bh)
__global__ __launch_bounds__(256) void transpose_v(
    const unsigned short* __restrict__ v, unsigned short* __restrict__ vt) {
  __shared__ unsigned short lds[64][66];
  const int tid = threadIdx.x;
  const int bh = blockIdx.y, t0 = blockIdx.x * 64;
  const unsigned short* src = v + ((size_t)(bh >> 4) * 2048 + t0) * 1024u + (bh & 15) * 64;
  unsigned short* dst = vt + (size_t)bh * 131072u + t0;
#pragma unroll
  for (int it = 0; it < 16; ++it) {
    int idx = it * 256 + tid;
    int r = idx >> 6, dd = idx & 63;          // read src[t=r][d=dd], coalesced
    lds[dd][r] = src[(size_t)r * 1024u + dd];
  }
  __syncthreads();
#pragma unroll
  for (int it = 0; it < 16; ++it) {
    int idx = it * 256 + tid;
    int dd = idx >> 6, r = idx & 63;          // write dst[d=dd][t=r], coalesced
    dst[(size_t)dd * 2048u + r] = lds[dd][r];
  }
}

// ---------------------------------------------------------------------------
// BT-GEMM: C[m][n] = sum_k A[m][k] * Bt[n][k]  (+ bias[n])
#define BM 128
#define BN 128
#define BK 32

template <int F32OUT>
__global__ __launch_bounds__(256) void gemm_bt(
    const unsigned short* __restrict__ A, const unsigned short* __restrict__ Bt,
    const float* __restrict__ bias, void* __restrict__ Cv,
    int M, int N, int K) {
  __shared__ __align__(16) unsigned short Al[BM * BK];
  __shared__ __align__(16) unsigned short Bl[BN * BK];
  const int tid = threadIdx.x;
  const int wid = tid >> 6, lane = tid & 63;
  const int l15 = lane & 15, lhi = lane >> 4;
  const int m0 = blockIdx.y * BM;
  const int n0 = blockIdx.x * BN;
  const int wr = wid >> 1, wc = wid & 1;
  const unsigned short* Btz = Bt + ((size_t)blockIdx.z << 20);

  f32x4 acc[4][4] = {};

  for (int k0 = 0; k0 < K; k0 += BK) {
#pragma unroll
    for (int j = 0; j < 2; ++j) {
      int q = tid + j * 256;         // chunk id 0..511
      int row = q >> 2, c = q & 3;   // [row][c*8..c*8+7]
      gload_lds16(A + (size_t)(m0 + row) * K + (k0 + c * 8), Al + q * 8);
      gload_lds16(Btz + (size_t)(n0 + row) * K + (k0 + c * 8), Bl + q * 8);
    }
    __syncthreads();
    bf16x8 af[4], bfr[4];
#pragma unroll
    for (int mi = 0; mi < 4; ++mi)
      af[mi] = *(const bf16x8*)(Al + (wr * 64 + mi * 16 + l15) * BK + lhi * 8);
#pragma unroll
    for (int ni = 0; ni < 4; ++ni)
      bfr[ni] = *(const bf16x8*)(Bl + (wc * 64 + ni * 16 + l15) * BK + lhi * 8);
#pragma unroll
    for (int mi = 0; mi < 4; ++mi)
#pragma unroll
      for (int ni = 0; ni < 4; ++ni)
        acc[mi][ni] = __builtin_amdgcn_mfma_f32_16x16x32_bf16(
            af[mi], bfr[ni], acc[mi][ni], 0, 0, 0);
    __syncthreads();
  }
#pragma unroll
  for (int mi = 0; mi < 4; ++mi) {
#pragma unroll
    for (int ni = 0; ni < 4; ++ni) {
      int n = n0 + wc * 64 + ni * 16 + l15;
      if constexpr (F32OUT) {
        float* Cz = (float*)Cv;
        float badd = bias[n];
#pragma unroll
        for (int r = 0; r < 4; ++r) {
          int m = m0 + wr * 64 + mi * 16 + lhi * 4 + r;
          Cz[(size_t)m * N + n] = acc[mi][ni][r] + badd;
        }
      } else {
        unsigned short* Cz = (unsigned short*)Cv + ((size_t)blockIdx.z << 23);
#pragma unroll
        for (int r = 0; r < 4; ++r) {
          int m = m0 + wr * 64 + mi * 16 + lhi * 4 + r;
          Cz[(size_t)m * N + n] = f2bf(acc[mi][ni][r]);
        }
      }
    }
  }
}

// ---------------------------------------------------------------------------
// Flash causal attention, swapped-operand softmax.
// One block = (b,h, q-tile PAIR {qt, 15-qt}): every block does 34 KV-tiles.
// 4 waves x 32 q-rows. KV tile 64. K/V^T staged via global_load_lds with
// XOR-chunk swizzle, double-buffered, one barrier per tile.
// QK^T computed SWAPPED: S^T = mfma(K, Q) -> lane holds one q-row's S values
// (q = lane&15 per 16-block, s = sj*16 + lhi*4 + r, consecutive in r):
//   * row max/sum: in-lane tree + 2 shfl_xor (16,32) instead of 4x8 shfl
//   * P packs as bf16x4 (consecutive s) -> 8 ds_write_b64 per tile
//   * PV reads P back as the A-fragment directly (4 ds_read_b128)
//   * defer-max (THR): skip rescale+redistribution when max doesn't grow
#define QT 128
#define KVT 64
#define PSTR 72
#define SCLOG2E 0.04508422f  // (1/32) * log2(e)
#define DTHR 128.0f          // defer-max threshold (unscaled S units; e^5.8 P bound)

__global__ __launch_bounds__(256) void attn_fwd(
    const unsigned short* __restrict__ Qg, const unsigned short* __restrict__ Kg,
    const unsigned short* __restrict__ Vtg, unsigned short* __restrict__ Og) {
  __shared__ __align__(16) unsigned short Kl[2][64 * 64];
  __shared__ __align__(16) unsigned short Vl[2][64 * 64];
  __shared__ __align__(16) unsigned short Pl[4][32 * PSTR];
  const int tid = threadIdx.x, wid = tid >> 6, lane = tid & 63;
  const int l15 = lane & 15, lhi = lane >> 4, x7 = lane & 7;
  const size_t base = (size_t)(blockIdx.y >> 4) * (2048u * 1024u) +
                      (size_t)(blockIdx.y & 15) * 64u;
  const size_t vtbase = (size_t)blockIdx.y * (64u * 2048u);
  const int qtA = blockIdx.x, qtB = 15 - qtA;
  const int n0 = 2 * (qtA + 1), n1 = 2 * (qtB + 1);
  const int ntot = n0 + n1;  // 34 for every block

  auto s0_of = [&](int g) { return ((g < n0) ? g : g - n0) * KVT; };

  auto stage = [&](int bufi, int s0) {
#pragma unroll
    for (int j = 0; j < 2; ++j) {
      int q = tid + j * 256;                 // 512 chunks of 16B per matrix
      int r = q >> 3;                        // row (s for K, d for Vt)
      int c = (q & 7) ^ (r & 7);             // inverse-swizzled source chunk
      gload_lds16(Kg + base + (size_t)(s0 + r) * 1024u + c * 8, &Kl[bufi][q * 8]);
      gload_lds16(Vtg + vtbase + (size_t)r * 2048u + s0 + c * 8, &Vl[bufi][q * 8]);
    }
  };

  stage(0, 0);
  __syncthreads();

  int g = 0;
  for (int pass = 0; pass < 2; ++pass) {
    const int qt = pass ? qtB : qtA;
    const int nt = pass ? n1 : n0;
    const int qrow0 = qt * QT + wid * 32;

    // Q fragments in registers (B-operand: cols q = fi*16 + l15, k = d)
    bf16x8 qf[2][2];
#pragma unroll
    for (int fi = 0; fi < 2; ++fi)
#pragma unroll
      for (int kj = 0; kj < 2; ++kj)
        qf[fi][kj] = *(const bf16x8*)(Qg + base +
            (size_t)(qrow0 + fi * 16 + l15) * 1024u + kj * 32 + lhi * 8);

    float mrun[2], lrun[2];
    f32x4 oacc[2][4] = {};
#pragma unroll
    for (int fi = 0; fi < 2; ++fi) { mrun[fi] = -1e30f; lrun[fi] = 0.0f; }

    for (int kt = 0; kt < nt; ++kt, ++g) {
      const int cur = g & 1;
      const int s0 = kt * KVT;
      if (g + 1 < ntot) stage(cur ^ 1, s0_of(g + 1));
      // wave-uniform: skip tiles fully above the causal diagonal for our rows
      if (s0 <= qrow0 + 31) {
        const bool notfull = (s0 + KVT - 1 > qrow0);  // needs masking
        const unsigned short* Kb = Kl[cur];
        const unsigned short* Vb = Vl[cur];

        // S^T = mfma(K, Q): lane holds S[s = s0+sj*16+lhi*4+r][q = qrow0+fi*16+l15]
        f32x4 sacc[2][4] = {};
#pragma unroll
        for (int kj = 0; kj < 2; ++kj) {
          bf16x8 kf[4];
#pragma unroll
          for (int sj = 0; sj < 4; ++sj) {
            int r = sj * 16 + l15;
            kf[sj] = *(const bf16x8*)(&Kb[r * 64 + (((kj * 4 + lhi) ^ x7) * 8)]);
          }
#pragma unroll
          for (int fi = 0; fi < 2; ++fi)
#pragma unroll
            for (int sj = 0; sj < 4; ++sj)
              sacc[fi][sj] = __builtin_amdgcn_mfma_f32_16x16x32_bf16(
                  kf[sj], qf[fi][kj], sacc[fi][sj], 0, 0, 0);
        }

        // causal mask + per-row (per-lane) tile max; reduce over 4 lhi lanes
        float tmax[2];
#pragma unroll
        for (int fi = 0; fi < 2; ++fi) {
          const int qa = qrow0 + fi * 16 + l15;
          float mx = -3e38f;
          if (notfull) {
#pragma unroll
            for (int sj = 0; sj < 4; ++sj)
#pragma unroll
              for (int r = 0; r < 4; ++r) {
                int sa = s0 + sj * 16 + lhi * 4 + r;
                float v = (sa <= qa) ? sacc[fi][sj][r] : -3e38f;
                sacc[fi][sj][r] = v;
                mx = fmaxf(mx, v);
              }
          } else {
#pragma unroll
            for (int sj = 0; sj < 4; ++sj)
#pragma unroll
              for (int r = 0; r < 4; ++r)
                mx = fmaxf(mx, sacc[fi][sj][r]);
          }
          mx = fmaxf(mx, __shfl_xor(mx, 16, 64));
          mx = fmaxf(mx, __shfl_xor(mx, 32, 64));
          tmax[fi] = mx;
        }

        // defer-max: only rescale when the running max actually grows
        bool needR = (tmax[0] > mrun[0] + DTHR) || (tmax[1] > mrun[1] + DTHR);
        if (__any(needR)) {
          float sc[2];
#pragma unroll
          for (int fi = 0; fi < 2; ++fi) {
            float mnew = fmaxf(mrun[fi], tmax[fi]);
            sc[fi] = EXP2F((mrun[fi] - mnew) * SCLOG2E);
            mrun[fi] = mnew;
            lrun[fi] *= sc[fi];
          }
          // redistribute sc from stats layout (q=l15) to oacc layout (q=lhi*4+r)
#pragma unroll
          for (int fi = 0; fi < 2; ++fi)
#pragma unroll
            for (int r = 0; r < 4; ++r) {
              float so = __shfl(sc[fi], (lane & 48) + lhi * 4 + r, 64);
#pragma unroll
              for (int dj = 0; dj < 4; ++dj) oacc[fi][dj][r] *= so;
            }
        }

        // P = exp2((S-m)*C): pack 4 consecutive-s bf16 per (fi,sj), b64 store
#pragma unroll
        for (int fi = 0; fi < 2; ++fi) {
          const float m = mrun[fi];
          float ps = 0.0f;
#pragma unroll
          for (int sj = 0; sj < 4; ++sj) {
            float p0 = EXP2F((sacc[fi][sj][0] - m) * SCLOG2E);
            float p1 = EXP2F((sacc[fi][sj][1] - m) * SCLOG2E);
            float p2 = EXP2F((sacc[fi][sj][2] - m) * SCLOG2E);
            float p3 = EXP2F((sacc[fi][sj][3] - m) * SCLOG2E);
            bf16x4 pk;
            pk[0] = (__bf16)p0; pk[1] = (__bf16)p1;
            pk[2] = (__bf16)p2; pk[3] = (__bf16)p3;
            *(bf16x4*)(&Pl[wid][(fi * 16 + l15) * PSTR + sj * 16 + lhi * 4]) = pk;
            ps += (p0 + p1) + (p2 + p3);
          }
          ps += __shfl_xor(ps, 16, 64);
          ps += __shfl_xor(ps, 32, 64);
          lrun[fi] += ps;
        }

        // O += P V  (A-op = P rows q=l15 from Pl, B-op = V^T rows from Vl)
#pragma unroll
        for (int kk = 0; kk < 2; ++kk) {
          bf16x8 pf[2], vf[4];
#pragma unroll
          for (int fi = 0; fi < 2; ++fi)
            pf[fi] = *(const bf16x8*)(&Pl[wid][(fi * 16 + l15) * PSTR + kk * 32 + lhi * 8]);
#pragma unroll
          for (int dj = 0; dj < 4; ++dj) {
            int r = dj * 16 + l15;
            vf[dj] = *(const bf16x8*)(&Vb[r * 64 + (((kk * 4 + lhi) ^ x7) * 8)]);
          }
#pragma unroll
          for (int fi = 0; fi < 2; ++fi)
#pragma unroll
            for (int dj = 0; dj < 4; ++dj)
              oacc[fi][dj] = __builtin_amdgcn_mfma_f32_16x16x32_bf16(
                  pf[fi], vf[dj], oacc[fi][dj], 0, 0, 0);
        }
      }

      __syncthreads();  // all reads of buf[cur] done; drains next-tile loads
    }

    // normalize + store this q-tile's rows (lrun redistributed once per pass)
#pragma unroll
    for (int fi = 0; fi < 2; ++fi) {
      float rn[4];
#pragma unroll
      for (int r = 0; r < 4; ++r)
        rn[r] = 1.0f / __shfl(lrun[fi], (lane & 48) + lhi * 4 + r, 64);
#pragma unroll
      for (int dj = 0; dj < 4; ++dj)
#pragma unroll
        for (int r = 0; r < 4; ++r) {
          int t = qrow0 + fi * 16 + lhi * 4 + r;
          Og[base + (size_t)t * 1024u + dj * 16 + l15] = f2bf(oacc[fi][dj][r] * rn[r]);
        }
    }
  }
}

// ---------------------------------------------------------------------------
extern "C" void kernel_launch(void* const* d_in, const int* in_sizes, int n_in,
                              void* d_out, int out_size, void* d_ws, size_t ws_size,
                              hipStream_t stream) {
  const float* x  = (const float*)d_in[0];
  const float* wq = (const float*)d_in[1];
  const float* wk = (const float*)d_in[2];
  const float* wv = (const float*)d_in[3];
  const float* wp = (const float*)d_in[4];
  const float* bp = (const float*)d_in[5];
  float* out = (float*)d_out;

  unsigned short* ws   = (unsigned short*)d_ws;
  unsigned short* x_bf = ws;                          // 8M elems
  unsigned short* wtq  = ws + ((size_t)8 << 20);      // 3M
  unsigned short* wtp  = ws + ((size_t)11 << 20);     // 1M
  unsigned short* qkv  = ws + ((size_t)12 << 20);     // 24M (q,k,v @ 8M stride)
  unsigned short* q    = qkv;
  unsigned short* kk   = qkv + ((size_t)8 << 20);
  unsigned short* vv   = qkv + ((size_t)16 << 20);
  unsigned short* att  = vv;                          // alias: v dead after transpose_v
  unsigned short* vt   = ws + ((size_t)36 << 20);     // 8M

  const int M = 8192, N = 1024, K = 1024;

  cvt_f32_bf16<<<4096, 256, 0, stream>>>(x, x_bf);
  transpose_qkv<<<dim3(16, 16, 3), 256, 0, stream>>>(wq, wk, wv, wtq);
  transpose_proj<<<dim3(16, 16), 256, 0, stream>>>(wp, wtp);
  gemm_bt<0><<<dim3(N / BN, M / BM, 3), 256, 0, stream>>>(x_bf, wtq, nullptr, qkv, M, N, K);
  transpose_v<<<dim3(32, 64), 256, 0, stream>>>(vv, vt);
  attn_fwd<<<dim3(8, 64), 256, 0, stream>>>(q, kk, vt, att);
  gemm_bt<1><<<dim3(N / BN, M / BM, 1), 256, 0, stream>>>(att, wtp, bp, out, M, N, K);
}

// Round 7
// 199.525 us; speedup vs baseline: 2.4816x; 1.0537x over previous
//
#include <hip/hip_runtime.h>
#include <stdint.h>

// TimeSeriesAttention: x[B,T,C] -> per-head QKV -> causal softmax(QK^T/32) V -> proj
// B=4 T=2048 C=1024 H=16 D=64.
// Device I/O dtype: float32 (reference dtype). Internal compute: bf16 MFMA.
//
// ws layout (elements of bf16):
//   [0,    8M)  x_bf  [B*T][C]          bf16 copy of x
//   [8M,  11M)  wtq   3 x [n=h*64+d][k] transposed qkv weights (bf16)
//   [11M, 12M)  wtp   [c][k]            transposed proj weight (bf16)
//   [12M, 36M)  q,k,v [B*T][H*D]        each 8M elems
//   [28M, 36M)  att   ALIASES v (v is dead after transpose_v)
//   [36M, 44M)  vt    [B][H][64][2048]  V transposed per head
// total 44M bf16 elems = 88MB of d_ws.

typedef uint32_t u32;
typedef __bf16 bf16x8 __attribute__((ext_vector_type(8)));
typedef __bf16 bf16x4 __attribute__((ext_vector_type(4)));
typedef unsigned short us8 __attribute__((ext_vector_type(8)));
typedef float f32x4 __attribute__((ext_vector_type(4)));

#define EXP2F(x) __builtin_amdgcn_exp2f(x)   // v_exp_f32 (2^x)

static __device__ __forceinline__ unsigned short f2bf(float f) {
  union { float f; u32 i; } cv; cv.f = f;
  u32 x = cv.i;
  u32 r = (x + 0x7fffu + ((x >> 16) & 1u)) >> 16;  // RNE
  return (unsigned short)r;
}

// async global->LDS, 16B per lane; LDS dest is wave-uniform base + lane*16.
static __device__ __forceinline__ void gload_lds16(const unsigned short* g, unsigned short* l) {
  __builtin_amdgcn_global_load_lds(
      (__attribute__((address_space(1))) u32*)g,
      (__attribute__((address_space(3))) u32*)l, 16, 0, 0);
}

// ---------------------------------------------------------------------------
// x f32 -> bf16, 8 elems/thread
__global__ __launch_bounds__(256) void cvt_f32_bf16(
    const float* __restrict__ src, unsigned short* __restrict__ dst) {
  size_t i = (size_t)(blockIdx.x * 256 + threadIdx.x) * 8u;
  float4 a = *(const float4*)(src + i);
  float4 b = *(const float4*)(src + i + 4);
  us8 v;
  v[0] = f2bf(a.x); v[1] = f2bf(a.y); v[2] = f2bf(a.z); v[3] = f2bf(a.w);
  v[4] = f2bf(b.x); v[5] = f2bf(b.y); v[6] = f2bf(b.z); v[7] = f2bf(b.w);
  *(us8*)(dst + i) = v;
}

// ---------------------------------------------------------------------------
// wq/wk/wv [H][C][D] f32 -> wt [n=h*64+d][k=c] bf16, via 64x64 LDS tiles.
__global__ __launch_bounds__(256) void transpose_qkv(
    const float* __restrict__ wq, const float* __restrict__ wk,
    const float* __restrict__ wv, unsigned short* __restrict__ dst) {
  __shared__ unsigned short lds[64][66];
  const float* src = (blockIdx.z == 0) ? wq : (blockIdx.z == 1) ? wk : wv;
  unsigned short* d = dst + ((size_t)blockIdx.z << 20);
  const int tid = threadIdx.x;
  const int h = blockIdx.y, c0 = blockIdx.x * 64;
  const float* s = src + (size_t)h * 65536u + (size_t)c0 * 64u;
#pragma unroll
  for (int it = 0; it < 16; ++it) {
    int idx = it * 256 + tid;
    int r = idx >> 6, dd = idx & 63;          // read s[r][dd], coalesced
    lds[dd][r] = f2bf(s[r * 64 + dd]);
  }
  __syncthreads();
#pragma unroll
  for (int it = 0; it < 16; ++it) {
    int idx = it * 256 + tid;
    int dd = idx >> 6, r = idx & 63;          // write row h*64+dd, coalesced
    d[(size_t)(h * 64 + dd) * 1024u + c0 + r] = lds[dd][r];
  }
}

// w_proj [HD=1024][C=1024] f32 -> wtp [c][hd] bf16
__global__ __launch_bounds__(256) void transpose_proj(
    const float* __restrict__ wp, unsigned short* __restrict__ dst) {
  __shared__ unsigned short lds[64][66];
  const int tid = threadIdx.x;
  const int c0 = blockIdx.x * 64, r0 = blockIdx.y * 64;
#pragma unroll
  for (int it = 0; it < 16; ++it) {
    int idx = it * 256 + tid;
    int r = idx >> 6, cc = idx & 63;
    lds[cc][r] = f2bf(wp[(size_t)(r0 + r) * 1024u + c0 + cc]);
  }
  __syncthreads();
#pragma unroll
  for (int it = 0; it < 16; ++it) {
    int idx = it * 256 + tid;
    int cc = idx >> 6, r = idx & 63;
    dst[(size_t)(c0 + cc) * 1024u + r0 + r] = lds[cc][r];
  }
}

// v [B*T][H*64] bf16 -> vt [(b*16+h)*64+d][T=2048] bf16. grid (32 t-tiles, 64 bh)
__global__ __launch_bounds__(256) void transpose_v(
    const unsigned short* __restrict__ v, unsigned short* __restrict__ vt) {
  __shared__ unsigned short lds[64][66];
  const int tid = threadIdx.x;
  const int bh = blockIdx.y, t0 = blockIdx.x * 64;
  const unsigned short* src = v + ((size_t)(bh >> 4) * 2048 + t0) * 1024u + (bh & 15) * 64;
  unsigned short* dst = vt + (size_t)bh * 131072u + t0;
#pragma unroll
  for (int it = 0; it < 16; ++it) {
    int idx = it * 256 + tid;
    int r = idx >> 6, dd = idx & 63;          // read src[t=r][d=dd], coalesced
    lds[dd][r] = src[(size_t)r * 1024u + dd];
  }
  __syncthreads();
#pragma unroll
  for (int it = 0; it < 16; ++it) {
    int idx = it * 256 + tid;
    int dd = idx >> 6, r = idx & 63;          // write dst[d=dd][t=r], coalesced
    dst[(size_t)dd * 2048u + r] = lds[dd][r];
  }
}

// ---------------------------------------------------------------------------
// BT-GEMM: C[m][n] = sum_k A[m][k] * Bt[n][k]  (+ bias[n])
#define BM 128
#define BN 128
#define BK 32

template <int F32OUT>
__global__ __launch_bounds__(256) void gemm_bt(
    const unsigned short* __restrict__ A, const unsigned short* __restrict__ Bt,
    const float* __restrict__ bias, void* __restrict__ Cv,
    int M, int N, int K) {
  __shared__ __align__(16) unsigned short Al[BM * BK];
  __shared__ __align__(16) unsigned short Bl[BN * BK];
  const int tid = threadIdx.x;
  const int wid = tid >> 6, lane = tid & 63;
  const int l15 = lane & 15, lhi = lane >> 4;
  const int m0 = blockIdx.y * BM;
  const int n0 = blockIdx.x * BN;
  const int wr = wid >> 1, wc = wid & 1;
  const unsigned short* Btz = Bt + ((size_t)blockIdx.z << 20);

  f32x4 acc[4][4] = {};

  for (int k0 = 0; k0 < K; k0 += BK) {
#pragma unroll
    for (int j = 0; j < 2; ++j) {
      int q = tid + j * 256;         // chunk id 0..511
      int row = q >> 2, c = q & 3;   // [row][c*8..c*8+7]
      gload_lds16(A + (size_t)(m0 + row) * K + (k0 + c * 8), Al + q * 8);
      gload_lds16(Btz + (size_t)(n0 + row) * K + (k0 + c * 8), Bl + q * 8);
    }
    __syncthreads();
    bf16x8 af[4], bfr[4];
#pragma unroll
    for (int mi = 0; mi < 4; ++mi)
      af[mi] = *(const bf16x8*)(Al + (wr * 64 + mi * 16 + l15) * BK + lhi * 8);
#pragma unroll
    for (int ni = 0; ni < 4; ++ni)
      bfr[ni] = *(const bf16x8*)(Bl + (wc * 64 + ni * 16 + l15) * BK + lhi * 8);
#pragma unroll
    for (int mi = 0; mi < 4; ++mi)
#pragma unroll
      for (int ni = 0; ni < 4; ++ni)
        acc[mi][ni] = __builtin_amdgcn_mfma_f32_16x16x32_bf16(
            af[mi], bfr[ni], acc[mi][ni], 0, 0, 0);
    __syncthreads();
  }
#pragma unroll
  for (int mi = 0; mi < 4; ++mi) {
#pragma unroll
    for (int ni = 0; ni < 4; ++ni) {
      int n = n0 + wc * 64 + ni * 16 + l15;
      if constexpr (F32OUT) {
        float* Cz = (float*)Cv;
        float badd = bias[n];
#pragma unroll
        for (int r = 0; r < 4; ++r) {
          int m = m0 + wr * 64 + mi * 16 + lhi * 4 + r;
          Cz[(size_t)m * N + n] = acc[mi][ni][r] + badd;
        }
      } else {
        unsigned short* Cz = (unsigned short*)Cv + ((size_t)blockIdx.z << 23);
#pragma unroll
        for (int r = 0; r < 4; ++r) {
          int m = m0 + wr * 64 + mi * 16 + lhi * 4 + r;
          Cz[(size_t)m * N + n] = f2bf(acc[mi][ni][r]);
        }
      }
    }
  }
}

// ---------------------------------------------------------------------------
// Flash causal attention, swapped-operand softmax, 8 waves x 16 q-rows.
// One block = (b,h, q-tile PAIR {qt, 15-qt}): every block does 34 KV-tiles.
// 512 threads; 512 blocks = 2 blocks/CU -> 16 waves/CU (4/SIMD) for VALU
// latency hiding. KV tile 64; K/V^T staged via global_load_lds + XOR-chunk
// swizzle, double-buffered, one barrier per tile.
// S^T = mfma(K, Q): lane holds one q-row's S (q=lane&15, s=sj*16+lhi*4+r).
#define QT 128
#define KVT 64
#define PSTR 72
#define SCLOG2E 0.04508422f  // (1/32) * log2(e)
#define DTHR 128.0f          // defer-max threshold (unscaled S units)

__global__ __launch_bounds__(512, 4) void attn_fwd(
    const unsigned short* __restrict__ Qg, const unsigned short* __restrict__ Kg,
    const unsigned short* __restrict__ Vtg, unsigned short* __restrict__ Og) {
  __shared__ __align__(16) unsigned short Kl[2][64 * 64];
  __shared__ __align__(16) unsigned short Vl[2][64 * 64];
  __shared__ __align__(16) unsigned short Pl[8][16 * PSTR];
  const int tid = threadIdx.x, wid = tid >> 6, lane = tid & 63;
  const int l15 = lane & 15, lhi = lane >> 4, x7 = lane & 7;
  const size_t base = (size_t)(blockIdx.y >> 4) * (2048u * 1024u) +
                      (size_t)(blockIdx.y & 15) * 64u;
  const size_t vtbase = (size_t)blockIdx.y * (64u * 2048u);
  const int qtA = blockIdx.x, qtB = 15 - qtA;
  const int n0 = 2 * (qtA + 1), n1 = 2 * (qtB + 1);
  const int ntot = n0 + n1;  // 34 for every block

  auto s0_of = [&](int g) { return ((g < n0) ? g : g - n0) * KVT; };

  auto stage = [&](int bufi, int s0) {
    int q = tid;                           // 512 chunks of 16B per matrix
    int r = q >> 3;                        // row (s for K, d for Vt)
    int c = (q & 7) ^ (r & 7);             // inverse-swizzled source chunk
    gload_lds16(Kg + base + (size_t)(s0 + r) * 1024u + c * 8, &Kl[bufi][q * 8]);
    gload_lds16(Vtg + vtbase + (size_t)r * 2048u + s0 + c * 8, &Vl[bufi][q * 8]);
  };

  stage(0, 0);
  __syncthreads();

  int g = 0;
  for (int pass = 0; pass < 2; ++pass) {
    const int qt = pass ? qtB : qtA;
    const int nt = pass ? n1 : n0;
    const int qrow0 = qt * QT + wid * 16;  // this wave's 16-row band

    // Q fragments in registers (B-operand: cols q = l15, k = d)
    bf16x8 qf[2];
#pragma unroll
    for (int kj = 0; kj < 2; ++kj)
      qf[kj] = *(const bf16x8*)(Qg + base +
          (size_t)(qrow0 + l15) * 1024u + kj * 32 + lhi * 8);

    float mrun = -1e30f, lrun = 0.0f;
    f32x4 oacc[4] = {};

    for (int kt = 0; kt < nt; ++kt, ++g) {
      const int cur = g & 1;
      const int s0 = kt * KVT;
      if (g + 1 < ntot) stage(cur ^ 1, s0_of(g + 1));
      // wave-uniform: skip tiles fully above the causal diagonal for our rows
      if (s0 <= qrow0 + 15) {
        const bool notfull = (s0 + KVT - 1 > qrow0);  // needs masking
        const unsigned short* Kb = Kl[cur];
        const unsigned short* Vb = Vl[cur];

        // S^T = mfma(K, Q): lane holds S[s = s0+sj*16+lhi*4+r][q = qrow0+l15]
        f32x4 sacc[4] = {};
#pragma unroll
        for (int kj = 0; kj < 2; ++kj) {
          bf16x8 kf[4];
#pragma unroll
          for (int sj = 0; sj < 4; ++sj) {
            int r = sj * 16 + l15;
            kf[sj] = *(const bf16x8*)(&Kb[r * 64 + (((kj * 4 + lhi) ^ x7) * 8)]);
          }
#pragma unroll
          for (int sj = 0; sj < 4; ++sj)
            sacc[sj] = __builtin_amdgcn_mfma_f32_16x16x32_bf16(
                kf[sj], qf[kj], sacc[sj], 0, 0, 0);
        }

        // causal mask + per-q-row (per-lane) tile max; reduce over lhi groups
        const int qa = qrow0 + l15;
        float mx = -3e38f;
        if (notfull) {
#pragma unroll
          for (int sj = 0; sj < 4; ++sj)
#pragma unroll
            for (int r = 0; r < 4; ++r) {
              int sa = s0 + sj * 16 + lhi * 4 + r;
              float v = (sa <= qa) ? sacc[sj][r] : -3e38f;
              sacc[sj][r] = v;
              mx = fmaxf(mx, v);
            }
        } else {
#pragma unroll
          for (int sj = 0; sj < 4; ++sj)
#pragma unroll
            for (int r = 0; r < 4; ++r)
              mx = fmaxf(mx, sacc[sj][r]);
        }
        mx = fmaxf(mx, __shfl_xor(mx, 16, 64));
        mx = fmaxf(mx, __shfl_xor(mx, 32, 64));

        // defer-max: only rescale when the running max grows materially
        if (__any(mx > mrun + DTHR)) {
          float mnew = fmaxf(mrun, mx);
          float sc = EXP2F((mrun - mnew) * SCLOG2E);
          mrun = mnew;
          lrun *= sc;
          // redistribute sc from stats layout (q=l15) to oacc layout (q=lhi*4+r)
#pragma unroll
          for (int r = 0; r < 4; ++r) {
            float so = __shfl(sc, (lane & 48) + lhi * 4 + r, 64);
#pragma unroll
            for (int dj = 0; dj < 4; ++dj) oacc[dj][r] *= so;
          }
        }

        // P = exp2((S-m)*C): pack 4 consecutive-s bf16 per sj, b64 store
        {
          const float m = mrun;
          float ps = 0.0f;
#pragma unroll
          for (int sj = 0; sj < 4; ++sj) {
            float p0 = EXP2F((sacc[sj][0] - m) * SCLOG2E);
            float p1 = EXP2F((sacc[sj][1] - m) * SCLOG2E);
            float p2 = EXP2F((sacc[sj][2] - m) * SCLOG2E);
            float p3 = EXP2F((sacc[sj][3] - m) * SCLOG2E);
            bf16x4 pk;
            pk[0] = (__bf16)p0; pk[1] = (__bf16)p1;
            pk[2] = (__bf16)p2; pk[3] = (__bf16)p3;
            *(bf16x4*)(&Pl[wid][l15 * PSTR + sj * 16 + lhi * 4]) = pk;
            ps += (p0 + p1) + (p2 + p3);
          }
          ps += __shfl_xor(ps, 16, 64);
          ps += __shfl_xor(ps, 32, 64);
          lrun += ps;
        }

        // O += P V  (A-op = P rows q=l15 from Pl, B-op = V^T rows from Vl)
#pragma unroll
        for (int kk = 0; kk < 2; ++kk) {
          bf16x8 pf, vf[4];
          pf = *(const bf16x8*)(&Pl[wid][l15 * PSTR + kk * 32 + lhi * 8]);
#pragma unroll
          for (int dj = 0; dj < 4; ++dj) {
            int r = dj * 16 + l15;
            vf[dj] = *(const bf16x8*)(&Vb[r * 64 + (((kk * 4 + lhi) ^ x7) * 8)]);
          }
#pragma unroll
          for (int dj = 0; dj < 4; ++dj)
            oacc[dj] = __builtin_amdgcn_mfma_f32_16x16x32_bf16(
                pf, vf[dj], oacc[dj], 0, 0, 0);
        }
      }

      __syncthreads();  // all reads of buf[cur] done; drains next-tile loads
    }

    // normalize + store this q-band's rows (lrun redistributed once per pass)
    float rn[4];
#pragma unroll
    for (int r = 0; r < 4; ++r)
      rn[r] = 1.0f / __shfl(lrun, (lane & 48) + lhi * 4 + r, 64);
#pragma unroll
    for (int dj = 0; dj < 4; ++dj)
#pragma unroll
      for (int r = 0; r < 4; ++r) {
        int t = qrow0 + lhi * 4 + r;
        Og[base + (size_t)t * 1024u + dj * 16 + l15] = f2bf(oacc[dj][r] * rn[r]);
      }
  }
}

// ---------------------------------------------------------------------------
extern "C" void kernel_launch(void* const* d_in, const int* in_sizes, int n_in,
                              void* d_out, int out_size, void* d_ws, size_t ws_size,
                              hipStream_t stream) {
  const float* x  = (const float*)d_in[0];
  const float* wq = (const float*)d_in[1];
  const float* wk = (const float*)d_in[2];
  const float* wv = (const float*)d_in[3];
  const float* wp = (const float*)d_in[4];
  const float* bp = (const float*)d_in[5];
  float* out = (float*)d_out;

  unsigned short* ws   = (unsigned short*)d_ws;
  unsigned short* x_bf = ws;                          // 8M elems
  unsigned short* wtq  = ws + ((size_t)8 << 20);      // 3M
  unsigned short* wtp  = ws + ((size_t)11 << 20);     // 1M
  unsigned short* qkv  = ws + ((size_t)12 << 20);     // 24M (q,k,v @ 8M stride)
  unsigned short* q    = qkv;
  unsigned short* kk   = qkv + ((size_t)8 << 20);
  unsigned short* vv   = qkv + ((size_t)16 << 20);
  unsigned short* att  = vv;                          // alias: v dead after transpose_v
  unsigned short* vt   = ws + ((size_t)36 << 20);     // 8M

  const int M = 8192, N = 1024, K = 1024;

  cvt_f32_bf16<<<4096, 256, 0, stream>>>(x, x_bf);
  transpose_qkv<<<dim3(16, 16, 3), 256, 0, stream>>>(wq, wk, wv, wtq);
  transpose_proj<<<dim3(16, 16), 256, 0, stream>>>(wp, wtp);
  gemm_bt<0><<<dim3(N / BN, M / BM, 3), 256, 0, stream>>>(x_bf, wtq, nullptr, qkv, M, N, K);
  transpose_v<<<dim3(32, 64), 256, 0, stream>>>(vv, vt);
  attn_fwd<<<dim3(8, 64), 512, 0, stream>>>(q, kk, vt, att);
  gemm_bt<1><<<dim3(N / BN, M / BM, 1), 256, 0, stream>>>(att, wtp, bp, out, M, N, K);
}

// Round 8
// 183.486 us; speedup vs baseline: 2.6986x; 1.0874x over previous
//
#include <hip/hip_runtime.h>
#include <stdint.h>

// TimeSeriesAttention: x[B,T,C] -> per-head QKV -> causal softmax(QK^T/32) V -> proj
// B=4 T=2048 C=1024 H=16 D=64.
// Device I/O dtype: float32 (reference dtype). Internal compute: bf16 MFMA.
//
// ws layout (elements of bf16):
//   [0,    8M)  x_bf  [B*T][C]          bf16 copy of x
//   [8M,  11M)  wtq   3 x [n=h*64+d][k] transposed qkv weights (bf16, contiguous
//                                        = one [3072][1024] B^T matrix)
//   [11M, 12M)  wtp   [c][k]            transposed proj weight (bf16)
//   [12M, 36M)  q,k,v [B*T][H*D]        each 8M elems
//   [28M, 36M)  att   ALIASES v (v is dead after transpose_v)
//   [36M, 44M)  vt    [B][H][64][2048]  V transposed per head
// total 44M bf16 elems = 88MB of d_ws.

typedef uint32_t u32;
typedef __bf16 bf16x8 __attribute__((ext_vector_type(8)));
typedef __bf16 bf16x4 __attribute__((ext_vector_type(4)));
typedef unsigned short us8 __attribute__((ext_vector_type(8)));
typedef float f32x4 __attribute__((ext_vector_type(4)));

#define EXP2F(x) __builtin_amdgcn_exp2f(x)   // v_exp_f32 (2^x)

static __device__ __forceinline__ unsigned short f2bf(float f) {
  union { float f; u32 i; } cv; cv.f = f;
  u32 x = cv.i;
  u32 r = (x + 0x7fffu + ((x >> 16) & 1u)) >> 16;  // RNE
  return (unsigned short)r;
}

// async global->LDS, 16B per lane; LDS dest is wave-uniform base + lane*16.
static __device__ __forceinline__ void gload_lds16(const unsigned short* g, unsigned short* l) {
  __builtin_amdgcn_global_load_lds(
      (__attribute__((address_space(1))) u32*)g,
      (__attribute__((address_space(3))) u32*)l, 16, 0, 0);
}

// ---------------------------------------------------------------------------
// x f32 -> bf16, 8 elems/thread
__global__ __launch_bounds__(256) void cvt_f32_bf16(
    const float* __restrict__ src, unsigned short* __restrict__ dst) {
  size_t i = (size_t)(blockIdx.x * 256 + threadIdx.x) * 8u;
  float4 a = *(const float4*)(src + i);
  float4 b = *(const float4*)(src + i + 4);
  us8 v;
  v[0] = f2bf(a.x); v[1] = f2bf(a.y); v[2] = f2bf(a.z); v[3] = f2bf(a.w);
  v[4] = f2bf(b.x); v[5] = f2bf(b.y); v[6] = f2bf(b.z); v[7] = f2bf(b.w);
  *(us8*)(dst + i) = v;
}

// ---------------------------------------------------------------------------
// wq/wk/wv [H][C][D] f32 -> wt [n=h*64+d][k=c] bf16, via 64x64 LDS tiles.
__global__ __launch_bounds__(256) void transpose_qkv(
    const float* __restrict__ wq, const float* __restrict__ wk,
    const float* __restrict__ wv, unsigned short* __restrict__ dst) {
  __shared__ unsigned short lds[64][66];
  const float* src = (blockIdx.z == 0) ? wq : (blockIdx.z == 1) ? wk : wv;
  unsigned short* d = dst + ((size_t)blockIdx.z << 20);
  const int tid = threadIdx.x;
  const int h = blockIdx.y, c0 = blockIdx.x * 64;
  const float* s = src + (size_t)h * 65536u + (size_t)c0 * 64u;
#pragma unroll
  for (int it = 0; it < 16; ++it) {
    int idx = it * 256 + tid;
    int r = idx >> 6, dd = idx & 63;          // read s[r][dd], coalesced
    lds[dd][r] = f2bf(s[r * 64 + dd]);
  }
  __syncthreads();
#pragma unroll
  for (int it = 0; it < 16; ++it) {
    int idx = it * 256 + tid;
    int dd = idx >> 6, r = idx & 63;          // write row h*64+dd, coalesced
    d[(size_t)(h * 64 + dd) * 1024u + c0 + r] = lds[dd][r];
  }
}

// w_proj [HD=1024][C=1024] f32 -> wtp [c][hd] bf16
__global__ __launch_bounds__(256) void transpose_proj(
    const float* __restrict__ wp, unsigned short* __restrict__ dst) {
  __shared__ unsigned short lds[64][66];
  const int tid = threadIdx.x;
  const int c0 = blockIdx.x * 64, r0 = blockIdx.y * 64;
#pragma unroll
  for (int it = 0; it < 16; ++it) {
    int idx = it * 256 + tid;
    int r = idx >> 6, cc = idx & 63;
    lds[cc][r] = f2bf(wp[(size_t)(r0 + r) * 1024u + c0 + cc]);
  }
  __syncthreads();
#pragma unroll
  for (int it = 0; it < 16; ++it) {
    int idx = it * 256 + tid;
    int cc = idx >> 6, r = idx & 63;
    dst[(size_t)(c0 + cc) * 1024u + r0 + r] = lds[cc][r];
  }
}

// v [B*T][H*64] bf16 -> vt [(b*16+h)*64+d][T=2048] bf16. grid (32 t-tiles, 64 bh)
__global__ __launch_bounds__(256) void transpose_v(
    const unsigned short* __restrict__ v, unsigned short* __restrict__ vt) {
  __shared__ unsigned short lds[64][66];
  const int tid = threadIdx.x;
  const int bh = blockIdx.y, t0 = blockIdx.x * 64;
  const unsigned short* src = v + ((size_t)(bh >> 4) * 2048 + t0) * 1024u + (bh & 15) * 64;
  unsigned short* dst = vt + (size_t)bh * 131072u + t0;
#pragma unroll
  for (int it = 0; it < 16; ++it) {
    int idx = it * 256 + tid;
    int r = idx >> 6, dd = idx & 63;
    lds[dd][r] = src[(size_t)r * 1024u + dd];
  }
  __syncthreads();
#pragma unroll
  for (int it = 0; it < 16; ++it) {
    int idx = it * 256 + tid;
    int dd = idx >> 6, r = idx & 63;
    dst[(size_t)dd * 2048u + r] = lds[dd][r];
  }
}

// ---------------------------------------------------------------------------
// 256x256 8-phase BT-GEMM (T2+T3+T4+T5). K=1024 fixed, BK=64 (16 K-tiles,
// 8 iterations of 2 K-tiles). 8 waves (2M x 4N), per-wave 128x64 output
// (acc[8][4] f32x4). LDS 128 KiB dynamic: A[2][256*64] | B[2][256*64], bf16,
// chunk-XOR swizzle c ^= (row&7) on 16B chunks (both-sides: pre-swizzled
// global source for the linear gload_lds dest; swizzled ds_read_b128).
// Phase quadrants p0..p3 = (mh,nh) (0,0)(0,1)(1,0)(1,1) on slot0 tile 2j;
// p4..p7 same on slot1 tile 2j+1. Staging (1-2 half-tiles/phase):
//   p0: A.h1(2j+1)->s1 | p2: B.h0(2j+2)->s0 | p3: B.h1+A.h0(2j+2)->s0
//   p4: A.h1(2j+2)->s0 | p6: B.h0(2j+3)->s1 | p7: B.h1+A.h0(2j+3)->s1
// s_waitcnt vmcnt(6) only at p3/p7 (leaves exactly 3 half-tiles in flight;
// guarantees the next group's whole K-tile landed). Last iter: vmcnt(0).
static __device__ __forceinline__ void g8_ldA(bf16x8 af[4][2], const unsigned short* As,
                                              int wmbase, int mh, int l15, int lhi) {
#pragma unroll
  for (int mi = 0; mi < 4; ++mi)
#pragma unroll
    for (int ks = 0; ks < 2; ++ks) {
      int row = wmbase + mh * 64 + mi * 16 + l15;
      int c = ((ks << 2) | lhi) ^ (row & 7);
      af[mi][ks] = *(const bf16x8*)(As + row * 64 + c * 8);
    }
}
static __device__ __forceinline__ void g8_ldB(bf16x8 bf[2][2], const unsigned short* Bs,
                                              int wnbase, int nh, int l15, int lhi) {
#pragma unroll
  for (int ni = 0; ni < 2; ++ni)
#pragma unroll
    for (int ks = 0; ks < 2; ++ks) {
      int row = wnbase + nh * 32 + ni * 16 + l15;
      int c = ((ks << 2) | lhi) ^ (row & 7);
      bf[ni][ks] = *(const bf16x8*)(Bs + row * 64 + c * 8);
    }
}
static __device__ __forceinline__ void g8_quad(f32x4 acc[8][4], bf16x8 af[4][2],
                                               bf16x8 bf[2][2], int mb, int nb) {
#pragma unroll
  for (int ks = 0; ks < 2; ++ks)
#pragma unroll
    for (int mi = 0; mi < 4; ++mi)
#pragma unroll
      for (int ni = 0; ni < 2; ++ni)
        acc[mb + mi][nb + ni] = __builtin_amdgcn_mfma_f32_16x16x32_bf16(
            af[mi][ks], bf[ni][ks], acc[mb + mi][nb + ni], 0, 0, 0);
}
// stage one 128x64 half-tile (1024 chunks of 16B; 2 loads/thread)
static __device__ __forceinline__ void g8_stage(const unsigned short* g,
                                                unsigned short* d, int tid) {
#pragma unroll
  for (int l = 0; l < 2; ++l) {
    int cid = l * 512 + tid;
    int r = cid >> 3, c = cid & 7;
    int cs = c ^ (r & 7);
    gload_lds16(g + (size_t)r * 1024 + cs * 8, d + cid * 8);
  }
}

#define G8_BAR  __builtin_amdgcn_s_barrier()
#define G8_LGKM do { asm volatile("s_waitcnt lgkmcnt(0)" ::: "memory"); \
                     __builtin_amdgcn_sched_barrier(0); } while (0)
#define G8_VM6  asm volatile("s_waitcnt vmcnt(6)" ::: "memory")
#define G8_VM0  asm volatile("s_waitcnt vmcnt(0)" ::: "memory")

template <int F32OUT>
__global__ __launch_bounds__(512, 2) void gemm8p(
    const unsigned short* __restrict__ A, const unsigned short* __restrict__ Bt,
    const float* __restrict__ bias, void* __restrict__ Cv, int NXT) {
  extern __shared__ __align__(16) unsigned short ldsm[];
  unsigned short* Ab = ldsm;            // slot s: Ab + s*16384
  unsigned short* Bb = ldsm + 32768;    // slot s: Bb + s*16384
  const int tid = threadIdx.x, wid = tid >> 6, lane = tid & 63;
  const int l15 = lane & 15, lhi = lane >> 4;
  const int wmbase = (wid >> 2) * 128, wnbase = (wid & 3) * 64;
  // XCD-aware bijective swizzle (nwg % 8 == 0 for both grids)
  const int bid = blockIdx.x, cpx = (int)gridDim.x >> 3;
  const int wg = (bid & 7) * cpx + (bid >> 3);
  const int mt = wg / NXT, nt = wg - mt * NXT;
  const int m0 = mt * 256, n0 = nt * 256;

  f32x4 acc[8][4] = {};
  bf16x8 af[4][2], b0[2][2], b1[2][2];

  // prologue: tile0 (slot0) complete + tile1 (slot1) B.h0, B.h1, A.h0
  g8_stage(Bt + (size_t)(n0 + 0)   * 1024 + 0,  Bb + 0,     tid);
  g8_stage(Bt + (size_t)(n0 + 128) * 1024 + 0,  Bb + 8192,  tid);
  g8_stage(A  + (size_t)(m0 + 0)   * 1024 + 0,  Ab + 0,     tid);
  g8_stage(A  + (size_t)(m0 + 128) * 1024 + 0,  Ab + 8192,  tid);
  g8_stage(Bt + (size_t)(n0 + 0)   * 1024 + 64, Bb + 16384, tid);
  g8_stage(Bt + (size_t)(n0 + 128) * 1024 + 64, Bb + 24576, tid);
  g8_stage(A  + (size_t)(m0 + 0)   * 1024 + 64, Ab + 16384, tid);
  G8_VM6;
  G8_BAR;

  for (int j = 0; j < 8; ++j) {
    const bool last = (j == 7);
    const int kc = j * 128;  // k of tile 2j; +64/+128/+192 = tiles 2j+1/2/3
    // ---- group 0: slot0, tile 2j ----
    // p0
    g8_ldA(af, Ab, wmbase, 0, l15, lhi);
    g8_ldB(b0, Bb, wnbase, 0, l15, lhi);
    g8_stage(A + (size_t)(m0 + 128) * 1024 + (kc + 64), Ab + 24576, tid);
    G8_BAR; G8_LGKM;
    __builtin_amdgcn_s_setprio(1); g8_quad(acc, af, b0, 0, 0); __builtin_amdgcn_s_setprio(0);
    G8_BAR;
    // p1
    g8_ldB(b1, Bb, wnbase, 1, l15, lhi);
    G8_BAR; G8_LGKM;
    __builtin_amdgcn_s_setprio(1); g8_quad(acc, af, b1, 0, 2); __builtin_amdgcn_s_setprio(0);
    G8_BAR;
    // p2
    g8_ldA(af, Ab, wmbase, 1, l15, lhi);
    if (!last) g8_stage(Bt + (size_t)(n0 + 0) * 1024 + (kc + 128), Bb + 0, tid);
    G8_BAR; G8_LGKM;
    __builtin_amdgcn_s_setprio(1); g8_quad(acc, af, b0, 4, 0); __builtin_amdgcn_s_setprio(0);
    G8_BAR;
    // p3 (no ds_reads)
    if (!last) {
      g8_stage(Bt + (size_t)(n0 + 128) * 1024 + (kc + 128), Bb + 8192, tid);
      g8_stage(A  + (size_t)(m0 + 0)   * 1024 + (kc + 128), Ab + 0,    tid);
    }
    G8_BAR;
    __builtin_amdgcn_s_setprio(1); g8_quad(acc, af, b1, 4, 2); __builtin_amdgcn_s_setprio(0);
    if (last) { G8_VM0; } else { G8_VM6; }
    G8_BAR;
    // ---- group 1: slot1, tile 2j+1 ----
    // p4
    g8_ldA(af, Ab + 16384, wmbase, 0, l15, lhi);
    g8_ldB(b0, Bb + 16384, wnbase, 0, l15, lhi);
    if (!last) g8_stage(A + (size_t)(m0 + 128) * 1024 + (kc + 128), Ab + 8192, tid);
    G8_BAR; G8_LGKM;
    __builtin_amdgcn_s_setprio(1); g8_quad(acc, af, b0, 0, 0); __builtin_amdgcn_s_setprio(0);
    G8_BAR;
    // p5
    g8_ldB(b1, Bb + 16384, wnbase, 1, l15, lhi);
    G8_BAR; G8_LGKM;
    __builtin_amdgcn_s_setprio(1); g8_quad(acc, af, b1, 0, 2); __builtin_amdgcn_s_setprio(0);
    G8_BAR;
    // p6
    g8_ldA(af, Ab + 16384, wmbase, 1, l15, lhi);
    if (!last) g8_stage(Bt + (size_t)(n0 + 0) * 1024 + (kc + 192), Bb + 16384, tid);
    G8_BAR; G8_LGKM;
    __builtin_amdgcn_s_setprio(1); g8_quad(acc, af, b0, 4, 0); __builtin_amdgcn_s_setprio(0);
    G8_BAR;
    // p7 (no ds_reads)
    if (!last) {
      g8_stage(Bt + (size_t)(n0 + 128) * 1024 + (kc + 192), Bb + 24576, tid);
      g8_stage(A  + (size_t)(m0 + 0)   * 1024 + (kc + 192), Ab + 16384, tid);
    }
    G8_BAR;
    __builtin_amdgcn_s_setprio(1); g8_quad(acc, af, b1, 4, 2); __builtin_amdgcn_s_setprio(0);
    if (last) { G8_VM0; } else { G8_VM6; }
    G8_BAR;
  }

  // epilogue: C write (f32+bias or bf16 split into 3 z-arrays at n>>10)
#pragma unroll
  for (int mi = 0; mi < 8; ++mi) {
#pragma unroll
    for (int ni = 0; ni < 4; ++ni) {
      const int n = n0 + wnbase + ni * 16 + l15;
      const int mr = m0 + wmbase + mi * 16 + lhi * 4;
      if constexpr (F32OUT) {
        float* O = (float*)Cv;
        const float b = bias[n];
#pragma unroll
        for (int r = 0; r < 4; ++r)
          O[(size_t)(mr + r) * 1024 + n] = acc[mi][ni][r] + b;
      } else {
        unsigned short* O = (unsigned short*)Cv + ((size_t)(n >> 10) << 23);
        const int nc = n & 1023;
#pragma unroll
        for (int r = 0; r < 4; ++r)
          O[(size_t)(mr + r) * 1024 + nc] = f2bf(acc[mi][ni][r]);
      }
    }
  }
}

// ---------------------------------------------------------------------------
// Flash causal attention, swapped-operand softmax, 8 waves x 16 q-rows.
// (unchanged from round 7: 199.5us total, attn ~60us)
#define QT 128
#define KVT 64
#define PSTR 72
#define SCLOG2E 0.04508422f  // (1/32) * log2(e)
#define DTHR 128.0f          // defer-max threshold (unscaled S units)

__global__ __launch_bounds__(512, 4) void attn_fwd(
    const unsigned short* __restrict__ Qg, const unsigned short* __restrict__ Kg,
    const unsigned short* __restrict__ Vtg, unsigned short* __restrict__ Og) {
  __shared__ __align__(16) unsigned short Kl[2][64 * 64];
  __shared__ __align__(16) unsigned short Vl[2][64 * 64];
  __shared__ __align__(16) unsigned short Pl[8][16 * PSTR];
  const int tid = threadIdx.x, wid = tid >> 6, lane = tid & 63;
  const int l15 = lane & 15, lhi = lane >> 4, x7 = lane & 7;
  const size_t base = (size_t)(blockIdx.y >> 4) * (2048u * 1024u) +
                      (size_t)(blockIdx.y & 15) * 64u;
  const size_t vtbase = (size_t)blockIdx.y * (64u * 2048u);
  const int qtA = blockIdx.x, qtB = 15 - qtA;
  const int n0 = 2 * (qtA + 1), n1 = 2 * (qtB + 1);
  const int ntot = n0 + n1;  // 34 for every block

  auto s0_of = [&](int g) { return ((g < n0) ? g : g - n0) * KVT; };

  auto stage = [&](int bufi, int s0) {
    int q = tid;
    int r = q >> 3;
    int c = (q & 7) ^ (r & 7);
    gload_lds16(Kg + base + (size_t)(s0 + r) * 1024u + c * 8, &Kl[bufi][q * 8]);
    gload_lds16(Vtg + vtbase + (size_t)r * 2048u + s0 + c * 8, &Vl[bufi][q * 8]);
  };

  stage(0, 0);
  __syncthreads();

  int g = 0;
  for (int pass = 0; pass < 2; ++pass) {
    const int qt = pass ? qtB : qtA;
    const int nt = pass ? n1 : n0;
    const int qrow0 = qt * QT + wid * 16;

    bf16x8 qf[2];
#pragma unroll
    for (int kj = 0; kj < 2; ++kj)
      qf[kj] = *(const bf16x8*)(Qg + base +
          (size_t)(qrow0 + l15) * 1024u + kj * 32 + lhi * 8);

    float mrun = -1e30f, lrun = 0.0f;
    f32x4 oacc[4] = {};

    for (int kt = 0; kt < nt; ++kt, ++g) {
      const int cur = g & 1;
      const int s0 = kt * KVT;
      if (g + 1 < ntot) stage(cur ^ 1, s0_of(g + 1));
      if (s0 <= qrow0 + 15) {
        const bool notfull = (s0 + KVT - 1 > qrow0);
        const unsigned short* Kb = Kl[cur];
        const unsigned short* Vb = Vl[cur];

        f32x4 sacc[4] = {};
#pragma unroll
        for (int kj = 0; kj < 2; ++kj) {
          bf16x8 kf[4];
#pragma unroll
          for (int sj = 0; sj < 4; ++sj) {
            int r = sj * 16 + l15;
            kf[sj] = *(const bf16x8*)(&Kb[r * 64 + (((kj * 4 + lhi) ^ x7) * 8)]);
          }
#pragma unroll
          for (int sj = 0; sj < 4; ++sj)
            sacc[sj] = __builtin_amdgcn_mfma_f32_16x16x32_bf16(
                kf[sj], qf[kj], sacc[sj], 0, 0, 0);
        }

        const int qa = qrow0 + l15;
        float mx = -3e38f;
        if (notfull) {
#pragma unroll
          for (int sj = 0; sj < 4; ++sj)
#pragma unroll
            for (int r = 0; r < 4; ++r) {
              int sa = s0 + sj * 16 + lhi * 4 + r;
              float v = (sa <= qa) ? sacc[sj][r] : -3e38f;
              sacc[sj][r] = v;
              mx = fmaxf(mx, v);
            }
        } else {
#pragma unroll
          for (int sj = 0; sj < 4; ++sj)
#pragma unroll
            for (int r = 0; r < 4; ++r)
              mx = fmaxf(mx, sacc[sj][r]);
        }
        mx = fmaxf(mx, __shfl_xor(mx, 16, 64));
        mx = fmaxf(mx, __shfl_xor(mx, 32, 64));

        if (__any(mx > mrun + DTHR)) {
          float mnew = fmaxf(mrun, mx);
          float sc = EXP2F((mrun - mnew) * SCLOG2E);
          mrun = mnew;
          lrun *= sc;
#pragma unroll
          for (int r = 0; r < 4; ++r) {
            float so = __shfl(sc, (lane & 48) + lhi * 4 + r, 64);
#pragma unroll
            for (int dj = 0; dj < 4; ++dj) oacc[dj][r] *= so;
          }
        }

        {
          const float m = mrun;
          float ps = 0.0f;
#pragma unroll
          for (int sj = 0; sj < 4; ++sj) {
            float p0 = EXP2F((sacc[sj][0] - m) * SCLOG2E);
            float p1 = EXP2F((sacc[sj][1] - m) * SCLOG2E);
            float p2 = EXP2F((sacc[sj][2] - m) * SCLOG2E);
            float p3 = EXP2F((sacc[sj][3] - m) * SCLOG2E);
            bf16x4 pk;
            pk[0] = (__bf16)p0; pk[1] = (__bf16)p1;
            pk[2] = (__bf16)p2; pk[3] = (__bf16)p3;
            *(bf16x4*)(&Pl[wid][l15 * PSTR + sj * 16 + lhi * 4]) = pk;
            ps += (p0 + p1) + (p2 + p3);
          }
          ps += __shfl_xor(ps, 16, 64);
          ps += __shfl_xor(ps, 32, 64);
          lrun += ps;
        }

#pragma unroll
        for (int kk = 0; kk < 2; ++kk) {
          bf16x8 pf, vf[4];
          pf = *(const bf16x8*)(&Pl[wid][l15 * PSTR + kk * 32 + lhi * 8]);
#pragma unroll
          for (int dj = 0; dj < 4; ++dj) {
            int r = dj * 16 + l15;
            vf[dj] = *(const bf16x8*)(&Vb[r * 64 + (((kk * 4 + lhi) ^ x7) * 8)]);
          }
#pragma unroll
          for (int dj = 0; dj < 4; ++dj)
            oacc[dj] = __builtin_amdgcn_mfma_f32_16x16x32_bf16(
                pf, vf[dj], oacc[dj], 0, 0, 0);
        }
      }

      __syncthreads();
    }

    float rn[4];
#pragma unroll
    for (int r = 0; r < 4; ++r)
      rn[r] = 1.0f / __shfl(lrun, (lane & 48) + lhi * 4 + r, 64);
#pragma unroll
    for (int dj = 0; dj < 4; ++dj)
#pragma unroll
      for (int r = 0; r < 4; ++r) {
        int t = qrow0 + lhi * 4 + r;
        Og[base + (size_t)t * 1024u + dj * 16 + l15] = f2bf(oacc[dj][r] * rn[r]);
      }
  }
}

// ---------------------------------------------------------------------------
extern "C" void kernel_launch(void* const* d_in, const int* in_sizes, int n_in,
                              void* d_out, int out_size, void* d_ws, size_t ws_size,
                              hipStream_t stream) {
  const float* x  = (const float*)d_in[0];
  const float* wq = (const float*)d_in[1];
  const float* wk = (const float*)d_in[2];
  const float* wv = (const float*)d_in[3];
  const float* wp = (const float*)d_in[4];
  const float* bp = (const float*)d_in[5];
  float* out = (float*)d_out;

  unsigned short* ws   = (unsigned short*)d_ws;
  unsigned short* x_bf = ws;                          // 8M elems
  unsigned short* wtq  = ws + ((size_t)8 << 20);      // 3M ([3072][1024] B^T)
  unsigned short* wtp  = ws + ((size_t)11 << 20);     // 1M
  unsigned short* qkv  = ws + ((size_t)12 << 20);     // 24M (q,k,v @ 8M stride)
  unsigned short* q    = qkv;
  unsigned short* kk   = qkv + ((size_t)8 << 20);
  unsigned short* vv   = qkv + ((size_t)16 << 20);
  unsigned short* att  = vv;                          // alias: v dead after transpose_v
  unsigned short* vt   = ws + ((size_t)36 << 20);     // 8M

  (void)hipFuncSetAttribute(reinterpret_cast<const void*>(&gemm8p<0>),
                            hipFuncAttributeMaxDynamicSharedMemorySize, 131072);
  (void)hipFuncSetAttribute(reinterpret_cast<const void*>(&gemm8p<1>),
                            hipFuncAttributeMaxDynamicSharedMemorySize, 131072);

  cvt_f32_bf16<<<4096, 256, 0, stream>>>(x, x_bf);
  transpose_qkv<<<dim3(16, 16, 3), 256, 0, stream>>>(wq, wk, wv, wtq);
  transpose_proj<<<dim3(16, 16), 256, 0, stream>>>(wp, wtp);
  // merged QKV projection: M=8192, N=3072 (z = n>>10), K=1024. 32x12 tiles.
  gemm8p<0><<<384, 512, 131072, stream>>>(x_bf, wtq, nullptr, qkv, 12);
  transpose_v<<<dim3(32, 64), 256, 0, stream>>>(vv, vt);
  attn_fwd<<<dim3(8, 64), 512, 0, stream>>>(q, kk, vt, att);
  // output projection: M=8192, N=1024, f32 out + bias. 32x4 tiles.
  gemm8p<1><<<128, 512, 131072, stream>>>(att, wtp, bp, out, 4);
}